// Round 7
// baseline (372.514 us; speedup 1.0000x reference)
//
#include <hip/hip_runtime.h>

typedef _Float16 half_t;
typedef _Float16 f16x8 __attribute__((ext_vector_type(8)));
typedef _Float16 f16x4 __attribute__((ext_vector_type(4)));
typedef _Float16 f16x2 __attribute__((ext_vector_type(2)));
typedef float fx4 __attribute__((ext_vector_type(4)));

typedef __attribute__((address_space(1))) const unsigned int as1_cuint;
typedef __attribute__((address_space(3))) unsigned int as3_uint;

__device__ __forceinline__ void gld16(const void* g, void* l) {
    __builtin_amdgcn_global_load_lds((as1_cuint*)g, (as3_uint*)l, 16, 0, 0);
}

// ---------------------------------------------------------------------------
// GEMM: C[m][n] = sum_k A[m][k] * B[n][k]   (B row-major [N][K], i.e. B^T)
// 128x128 tile, K-step 32, 4 waves each computing a 64x64 quadrant.
// Best measured structure for the N=1024 / moderate-K call sites (R13).
// LDS swizzle: LDS slot (row,c) holds global chunk c ^ ((row>>1)&3).
// MODE 1: QKV epilogue: z=0,1 -> RoPE fused (pair via __shfl_xor lane^1,
//         angle via __sincosf; Q scaled 0.125); z=2 -> V^T [b,h,dk,s].
// MODE 4: split-K over blockIdx.z; fp16 partial store.
// ---------------------------------------------------------------------------
template<int MODE>
__global__ __launch_bounds__(256, 2)
void gemm_bt(const half_t* __restrict__ A,
             const half_t* __restrict__ B0, const half_t* __restrict__ B1,
             const half_t* __restrict__ B2,
             half_t* o0, half_t* o1, half_t* o2, half_t* o3,
             int M, int N, int K)
{
    __shared__ half_t sA[128 * 32];
    __shared__ half_t sB[128 * 32];
    const int tid = threadIdx.x;
    const int wid = tid >> 6, lane = tid & 63;
    const int lm = lane & 15, lg = lane >> 4;
    const int wr = wid >> 1, wc = wid & 1;
    const int m0 = blockIdx.x * 128, n0 = blockIdx.y * 128;

    const half_t* Bp = B0;
    half_t* outb = o0;
    if (MODE == 1) {
        if (blockIdx.z == 1) { Bp = B1; outb = o1; }
        else if (blockIdx.z == 2) { Bp = B2; outb = o2; }
    }
    if (MODE == 4) {
        if (blockIdx.z == 1) outb = o1;
        else if (blockIdx.z == 2) outb = o2;
        else if (blockIdx.z == 3) outb = o3;
    }

    int Keff = K, koff = 0;
    if (MODE == 4) { Keff = K / gridDim.z; koff = blockIdx.z * Keff; }

    const int srow = tid >> 2;
    const int scolb = ((tid & 3) ^ ((srow >> 1) & 3)) << 4;   // swizzled source chunk
    const char* gA = (const char*)(A + (size_t)(m0 + srow) * K + koff) + scolb;
    const char* gB = (const char*)(Bp + (size_t)(n0 + srow) * K + koff) + scolb;
    const size_t rstep = (size_t)64 * K * sizeof(half_t);
    char* lA = (char*)sA + tid * 16;
    char* lB = (char*)sB + tid * 16;

    const int ksw = (lm >> 1) & 3;                            // read-side key

    fx4 acc[4][4] = {};

    for (int kt = 0; kt < Keff; kt += 32) {
        gld16(gA, lA);
        gld16(gA + rstep, lA + 4096);
        gld16(gB, lB);
        gld16(gB + rstep, lB + 4096);
        gA += 64; gB += 64;
        __syncthreads();
        f16x8 aF[4], bF[4];
#pragma unroll
        for (int mi = 0; mi < 4; mi++)
            aF[mi] = *(const f16x8*)(sA + (wr * 64 + mi * 16 + lm) * 32 + (lg ^ ksw) * 8);
#pragma unroll
        for (int ni = 0; ni < 4; ni++)
            bF[ni] = *(const f16x8*)(sB + (wc * 64 + ni * 16 + lm) * 32 + (lg ^ ksw) * 8);
#pragma unroll
        for (int mi = 0; mi < 4; mi++)
#pragma unroll
            for (int ni = 0; ni < 4; ni++)
                acc[mi][ni] = __builtin_amdgcn_mfma_f32_16x16x32_f16(aF[mi], bF[ni], acc[mi][ni], 0, 0, 0);
        __syncthreads();
    }

#pragma unroll
    for (int mi = 0; mi < 4; mi++) {
#pragma unroll
        for (int ni = 0; ni < 4; ni++) {
#pragma unroll
            for (int r = 0; r < 4; r++) {
                int m = m0 + wr * 64 + mi * 16 + lg * 4 + r;
                int n = n0 + wc * 64 + ni * 16 + lm;
                float v = acc[mi][ni][r];
                size_t idx = (size_t)m * N + n;
                if (MODE == 1) {
                    int b = m >> 11, s = m & 2047, hh = n >> 6, dk = n & 63;
                    if (blockIdx.z == 2) {
                        outb[((size_t)(b * 16 + hh) * 64 + dk) * 2048 + s] = (half_t)v;
                    } else {
                        // fused RoPE: pair (dk even, dk odd) in lanes (lm, lm^1)
                        float pv = __shfl_xor(v, 1);
                        float f = __expf((float)(dk >> 1) * -0.28782313662f);
                        float c, sn;
                        __sincosf((float)s * f, &sn, &c);
                        float xe = (lm & 1) ? pv : v;
                        float xo = (lm & 1) ? v : pv;
                        float rv = (lm & 1) ? (sn * xe + c * xo) : (c * xe - sn * xo);
                        if (blockIdx.z == 0) rv *= 0.125f;
                        outb[((size_t)(b * 16 + hh) * 2048 + s) * 64 + dk] = (half_t)rv;
                    }
                } else {
                    outb[idx] = (half_t)v;     // plain / partial, coalesced
                }
            }
        }
    }
}

// ---------------------------------------------------------------------------
// 256-wide pipeline machinery for the SwiGLU dual GEMM (R10-R12, measured
// 84-90us vs 102us for the 2-phase version).  See KT256 comments.
// ---------------------------------------------------------------------------
#define L256(buf, half, sec) (lbase + (buf) * 65536 + (half) * 16384 + (sec) * 8192)

#define KT256(CUR)                                                            \
  {                                                                           \
    const int BO = (CUR) * 65536;                                             \
    const int st1 = (t < nt - 1), st2 = (t < nt - 2);                         \
    const int s1 = (t + 1) * 128, s2 = (t + 2) * 128;                         \
    f16x8 aLo[4][2], aHi[4][2], bA[2][2], bB[2][2];                           \
    /* ---- phase 1: (m-lo, n-lo) ---- */                                     \
    _Pragma("unroll") for (int mi = 0; mi < 4; mi++) {                        \
        aLo[mi][0] = *(const f16x8*)(aBase + BO + mi * 2048 + swz0);          \
        aLo[mi][1] = *(const f16x8*)(aBase + BO + mi * 2048 + swz1);          \
    }                                                                         \
    _Pragma("unroll") for (int ni = 0; ni < 2; ni++) {                        \
        bA[ni][0] = *(const f16x8*)(bBase + BO + ni * 2048 + swz0);           \
        bA[ni][1] = *(const f16x8*)(bBase + BO + ni * 2048 + swz1);           \
    }                                                                         \
    if (st1) { gld16(pB10 + s1, L256(1 - (CUR), 3, 0));                       \
               gld16(pB1h + s1, L256(1 - (CUR), 3, 1)); }                     \
    asm volatile("s_waitcnt lgkmcnt(8)" ::: "memory");                        \
    __builtin_amdgcn_s_barrier();                                             \
    asm volatile("s_waitcnt lgkmcnt(0)" ::: "memory");                        \
    __builtin_amdgcn_sched_barrier(0);                                        \
    __builtin_amdgcn_s_setprio(1);                                            \
    _Pragma("unroll") for (int kk = 0; kk < 2; kk++)                          \
      _Pragma("unroll") for (int mi = 0; mi < 4; mi++)                        \
        _Pragma("unroll") for (int ni = 0; ni < 2; ni++)                      \
          acc[mi][ni] = __builtin_amdgcn_mfma_f32_16x16x32_f16(aLo[mi][kk], bA[ni][kk], acc[mi][ni], 0, 0, 0); \
    __builtin_amdgcn_s_setprio(0);                                            \
    __builtin_amdgcn_s_barrier();                                             \
    /* ---- phase 2: (m-lo, n-hi) ---- */                                     \
    _Pragma("unroll") for (int ni = 0; ni < 2; ni++) {                        \
        bB[ni][0] = *(const f16x8*)(bBase + BO + (2 + ni) * 2048 + swz0);     \
        bB[ni][1] = *(const f16x8*)(bBase + BO + (2 + ni) * 2048 + swz1);     \
    }                                                                         \
    if (st2) { gld16(pA00 + s2, L256(CUR, 0, 0)); }                           \
    __builtin_amdgcn_s_barrier();                                             \
    asm volatile("s_waitcnt lgkmcnt(0)" ::: "memory");                        \
    __builtin_amdgcn_sched_barrier(0);                                        \
    __builtin_amdgcn_s_setprio(1);                                            \
    _Pragma("unroll") for (int kk = 0; kk < 2; kk++)                          \
      _Pragma("unroll") for (int mi = 0; mi < 4; mi++)                        \
        _Pragma("unroll") for (int ni = 0; ni < 2; ni++)                      \
          acc[mi][2 + ni] = __builtin_amdgcn_mfma_f32_16x16x32_f16(aLo[mi][kk], bB[ni][kk], acc[mi][2 + ni], 0, 0, 0); \
    __builtin_amdgcn_s_setprio(0);                                            \
    __builtin_amdgcn_s_barrier();                                             \
    /* ---- phase 3: (m-hi, n-hi) ---- */                                     \
    _Pragma("unroll") for (int mi = 0; mi < 4; mi++) {                        \
        aHi[mi][0] = *(const f16x8*)(aBase + BO + (4 + mi) * 2048 + swz0);    \
        aHi[mi][1] = *(const f16x8*)(aBase + BO + (4 + mi) * 2048 + swz1);    \
    }                                                                         \
    if (st2) { gld16(pB00 + s2, L256(CUR, 2, 0));                             \
               gld16(pB0h + s2, L256(CUR, 2, 1)); }                           \
    __builtin_amdgcn_s_barrier();                                             \
    asm volatile("s_waitcnt lgkmcnt(0)" ::: "memory");                        \
    __builtin_amdgcn_sched_barrier(0);                                        \
    __builtin_amdgcn_s_setprio(1);                                            \
    _Pragma("unroll") for (int kk = 0; kk < 2; kk++)                          \
      _Pragma("unroll") for (int mi = 0; mi < 4; mi++)                        \
        _Pragma("unroll") for (int ni = 0; ni < 2; ni++)                      \
          acc[4 + mi][2 + ni] = __builtin_amdgcn_mfma_f32_16x16x32_f16(aHi[mi][kk], bB[ni][kk], acc[4 + mi][2 + ni], 0, 0, 0); \
    __builtin_amdgcn_s_setprio(0);                                            \
    __builtin_amdgcn_s_barrier();                                             \
    /* ---- phase 4: (m-hi, n-lo) ---- */                                     \
    if (st2) { gld16(pA0h + s2, L256(CUR, 0, 1));                             \
               gld16(pA10 + s2, L256(CUR, 1, 0));                             \
               gld16(pA1h + s2, L256(CUR, 1, 1)); }                           \
    __builtin_amdgcn_s_barrier();                                             \
    __builtin_amdgcn_sched_barrier(0);                                        \
    __builtin_amdgcn_s_setprio(1);                                            \
    _Pragma("unroll") for (int kk = 0; kk < 2; kk++)                          \
      _Pragma("unroll") for (int mi = 0; mi < 4; mi++)                        \
        _Pragma("unroll") for (int ni = 0; ni < 2; ni++)                      \
          acc[4 + mi][ni] = __builtin_amdgcn_mfma_f32_16x16x32_f16(aHi[mi][kk], bA[ni][kk], acc[4 + mi][ni], 0, 0, 0); \
    __builtin_amdgcn_s_setprio(0);                                            \
    if (t < nt - 2)       { asm volatile("s_waitcnt vmcnt(6)" ::: "memory"); }\
    else if (t == nt - 2) { asm volatile("s_waitcnt vmcnt(0)" ::: "memory"); }\
    __builtin_amdgcn_s_barrier();                                             \
  }

#define PRO256()                                                              \
    gld16(pA00, L256(0, 0, 0));                                               \
    gld16(pB00, L256(0, 2, 0)); gld16(pB0h, L256(0, 2, 1));                   \
    gld16(pA0h, L256(0, 0, 1)); gld16(pA10, L256(0, 1, 0)); gld16(pA1h, L256(0, 1, 1)); \
    gld16(pB10, L256(0, 3, 0)); gld16(pB1h, L256(0, 3, 1));                   \
    gld16(pA00 + 128, L256(1, 0, 0));                                         \
    gld16(pB00 + 128, L256(1, 2, 0)); gld16(pB0h + 128, L256(1, 2, 1));       \
    gld16(pA0h + 128, L256(1, 0, 1)); gld16(pA10 + 128, L256(1, 1, 0)); gld16(pA1h + 128, L256(1, 1, 1)); \
    asm volatile("s_waitcnt vmcnt(6)" ::: "memory");                          \
    __builtin_amdgcn_s_barrier();

// ---------------------------------------------------------------------------
// Fused SwiGLU up+gate GEMM (256x128 half-tile pipeline + XCD swizzle).
// One 256x256 GEMM: B panel = [128 rows of w1 | 128 rows of w3]; wc<2 -> U,
// wc>=2 -> G.  Epilogue: G-waves publish acc via LDS, U-waves fuse silu(u)*g.
// ---------------------------------------------------------------------------
__global__ __launch_bounds__(512, 2)
void gemm_dual9(const half_t* __restrict__ A,
                const half_t* __restrict__ B1, const half_t* __restrict__ B2,
                half_t* __restrict__ out, int M, int N, int K)
{
    __shared__ half_t smem[65536];   // 128 KiB
    const int tid = threadIdx.x;
    const int wid = tid >> 6, lane = tid & 63;
    const int lm = lane & 15, lg = lane >> 4;
    const int wr = wid >> 2, wc = wid & 3;
    // XCD swizzle (grid 16x32 = 512, 512%8==0 -> simple bijection)
    const int flat = blockIdx.x + (blockIdx.y << 4);
    const int wg = (flat & 7) * 64 + (flat >> 3);
    const int m0 = (wg & 15) * 256, n0 = (wg >> 4) * 128;

    const size_t KB = (size_t)K * 2;
    const int srow = tid >> 3;
    const int schunk = (tid & 7) ^ (srow & 7);
    const char* pA  = (const char*)A  + (size_t)(m0 + srow) * KB + schunk * 16;
    const char* pB0 = (const char*)B1 + (size_t)(n0 + srow) * KB + schunk * 16;
    const char* pB1 = (const char*)B2 + (size_t)(n0 + srow) * KB + schunk * 16;
    const char* pA00 = pA;
    const char* pA0h = pA + 64 * KB;
    const char* pA10 = pA + 128 * KB;
    const char* pA1h = pA + 192 * KB;
    const char* pB00 = pB0;
    const char* pB0h = pB0 + 64 * KB;
    const char* pB10 = pB1;
    const char* pB1h = pB1 + 64 * KB;
    const int nt = 16;

    char* const lbase = (char*)smem + tid * 16;

    const int swz0 = ((lg ^ (lm & 7)) << 4);
    const int swz1 = (((4 + lg) ^ (lm & 7)) << 4);
    const char* aBase = (const char*)smem + wr * 16384 + lm * 128;
    const char* bBase = (const char*)smem + (2 + (wc >> 1)) * 16384 + (wc & 1) * 8192 + lm * 128;

    PRO256()

    fx4 acc[8][4] = {};

#pragma unroll 1
    for (int tt = 0; tt < 16; tt += 2) {
        { const int t = tt;     KT256(0) }
        { const int t = tt + 1; KT256(1) }
    }

    // ---- epilogue: G-waves publish frags via LDS, U-waves fuse silu(u)*g
    float* gb = (float*)smem;
    if (wc >= 2) {
        const int gw = wr * 2 + (wc - 2);
#pragma unroll
        for (int mi = 0; mi < 8; mi++)
#pragma unroll
            for (int ni = 0; ni < 4; ni++)
                *(fx4*)((char*)gb + ((((gw * 8 + mi) * 4 + ni) * 64 + lane) << 4)) = acc[mi][ni];
    }
    __syncthreads();
    if (wc < 2) {
        const int gw = wr * 2 + wc;
#pragma unroll
        for (int mi = 0; mi < 8; mi++)
#pragma unroll
            for (int ni = 0; ni < 4; ni++) {
                fx4 gv = *(const fx4*)((const char*)gb + ((((gw * 8 + mi) * 4 + ni) * 64 + lane) << 4));
#pragma unroll
                for (int r = 0; r < 4; r++) {
                    int m = m0 + wr * 128 + mi * 16 + lg * 4 + r;
                    int n = n0 + wc * 64 + ni * 16 + lm;
                    float u = acc[mi][ni][r], g = gv[r];
                    out[(size_t)m * N + n] = (half_t)(u / (1.f + __expf(-u)) * g);
                }
            }
    }
}

// ---------------------------------------------------------------------------
// Fused O-proj combine + residual + RMSNorm (split-K=2 partials):
//   t = x + p0 + p1;  outF = t;  outH = rmsnorm(t)*w  (fp16)
// ---------------------------------------------------------------------------
__global__ __launch_bounds__(256, 4)
void addnorm_k(const float* __restrict__ x,
               const half_t* __restrict__ p0, const half_t* __restrict__ p1,
               const float* __restrict__ w,
               float* __restrict__ outF, half_t* __restrict__ outH)
{
    int row = blockIdx.x * 4 + (threadIdx.x >> 6);
    int lane = threadIdx.x & 63;
    const float4* xr = (const float4*)(x + (size_t)row * 1024);
    const f16x4* p0r = (const f16x4*)(p0 + (size_t)row * 1024);
    const f16x4* p1r = (const f16x4*)(p1 + (size_t)row * 1024);
    float4 v[4];
    float s = 0.f;
#pragma unroll
    for (int i = 0; i < 4; i++) {
        float4 xv = xr[lane + 64 * i];
        f16x4 a0 = p0r[lane + 64 * i];
        f16x4 a1 = p1r[lane + 64 * i];
        v[i].x = xv.x + (float)a0[0] + (float)a1[0];
        v[i].y = xv.y + (float)a0[1] + (float)a1[1];
        v[i].z = xv.z + (float)a0[2] + (float)a1[2];
        v[i].w = xv.w + (float)a0[3] + (float)a1[3];
        s += v[i].x * v[i].x + v[i].y * v[i].y + v[i].z * v[i].z + v[i].w * v[i].w;
    }
#pragma unroll
    for (int o = 32; o > 0; o >>= 1) s += __shfl_xor(s, o);
    float inv = rsqrtf(s * (1.f / 1024.f) + 1e-5f);
    const float4* w4 = (const float4*)w;
    float4* oF = (float4*)(outF + (size_t)row * 1024);
    f16x4* oH = (f16x4*)(outH + (size_t)row * 1024);
#pragma unroll
    for (int i = 0; i < 4; i++) {
        oF[lane + 64 * i] = v[i];
        float4 wv = w4[lane + 64 * i];
        f16x4 ov = { (half_t)(v[i].x * inv * wv.x), (half_t)(v[i].y * inv * wv.y),
                     (half_t)(v[i].z * inv * wv.z), (half_t)(v[i].w * inv * wv.w) };
        oH[lane + 64 * i] = ov;
    }
}

// ---------------------------------------------------------------------------
// Split-K=4 combine: out = out + p0 + p1 + p2 + p3
// ---------------------------------------------------------------------------
__global__ __launch_bounds__(256, 8)
void reduce4_k(const half_t* __restrict__ p0, const half_t* __restrict__ p1,
               const half_t* __restrict__ p2, const half_t* __restrict__ p3,
               float* __restrict__ out, int n4)
{
    int i = blockIdx.x * 256 + threadIdx.x;
    if (i >= n4) return;
    float4 b = ((const float4*)out)[i];
    f16x4 a0 = ((const f16x4*)p0)[i];
    f16x4 a1 = ((const f16x4*)p1)[i];
    f16x4 a2 = ((const f16x4*)p2)[i];
    f16x4 a3 = ((const f16x4*)p3)[i];
    float4 o = { b.x + (float)a0[0] + (float)a1[0] + (float)a2[0] + (float)a3[0],
                 b.y + (float)a0[1] + (float)a1[1] + (float)a2[1] + (float)a3[1],
                 b.z + (float)a0[2] + (float)a1[2] + (float)a2[2] + (float)a3[2],
                 b.w + (float)a0[3] + (float)a1[3] + (float)a2[3] + (float)a3[3] };
    ((float4*)out)[i] = o;
}

// ---------------------------------------------------------------------------
// Fused: cast 7 weight matrices fp32->fp16 (y<7) + RMSNorm of x (y==7)
// ---------------------------------------------------------------------------
struct CastA { const float* s; half_t* d; int n4; };
struct CastArgs { CastA a[7]; };

__global__ __launch_bounds__(256)
void cast_rms_k(CastArgs ca, const float* __restrict__ x,
                const float* __restrict__ w, half_t* __restrict__ out)
{
    if (blockIdx.y < 7) {
        CastA a = ca.a[blockIdx.y];
        int i = blockIdx.x * 256 + threadIdx.x;
        if (i >= a.n4) return;
        float4 v = ((const float4*)a.s)[i];
        ((f16x4*)a.d)[i] = (f16x4){ (half_t)v.x, (half_t)v.y, (half_t)v.z, (half_t)v.w };
        return;
    }
    if (blockIdx.x >= 1024) return;
    int row = blockIdx.x * 4 + (threadIdx.x >> 6);
    int lane = threadIdx.x & 63;
    const float4* xr = (const float4*)(x + (size_t)row * 1024);
    float4 v[4];
    float s = 0.f;
#pragma unroll
    for (int i = 0; i < 4; i++) {
        v[i] = xr[lane + 64 * i];
        s += v[i].x * v[i].x + v[i].y * v[i].y + v[i].z * v[i].z + v[i].w * v[i].w;
    }
#pragma unroll
    for (int o = 32; o > 0; o >>= 1) s += __shfl_xor(s, o);
    float inv = rsqrtf(s * (1.f / 1024.f) + 1e-5f);
    const float4* w4 = (const float4*)w;
    f16x4* o4 = (f16x4*)(out + (size_t)row * 1024);
#pragma unroll
    for (int i = 0; i < 4; i++) {
        float4 wv = w4[lane + 64 * i];
        f16x4 ov = { (half_t)(v[i].x * inv * wv.x), (half_t)(v[i].y * inv * wv.y),
                     (half_t)(v[i].z * inv * wv.z), (half_t)(v[i].w * inv * wv.w) };
        o4[lane + 64 * i] = ov;
    }
}

// ---------------------------------------------------------------------------
// Causal flash attention, R15: 8-wave paired-tile structure.
// Q,K: [b,h,s,64] (RoPE pre-applied, Q pre-scaled).  VT: [b,h,dk,s].
// Waves 0-3 own q-tile qt=p (16 rows each), waves 4-7 own qt=31-p; one
// shared K/V staging pass covers the union (nTL=(33-p)/2 tiles) -- K/V
// loaded ONCE per block (was twice), serial span max instead of sum.
// 512 thr, LDS 80 KB (K dbuf 32K + V 16K + sP 32K) -> 2 blocks/CU =
// 4 waves/SIMD (was 2): doubles latency-hiding TLP for the serial
// QK->exp->PV chain.  K double-buffered (issued tile-top); V single-
// buffered (issued post-PV-barrier, covered by next tile's QK+exp).
// Two __syncthreads/tile: B2 = "V(t),K(t) landed", B1 = "PV reads done".
// Short-range waves gate compute on t<nTs but hit all barriers.
// XCD swizzle: each XCD owns 4 complete heads -> K/V L2-resident.
// ---------------------------------------------------------------------------
__global__ __launch_bounds__(512, 4)
void attn_k(const half_t* __restrict__ Q, const half_t* __restrict__ K,
            const half_t* __restrict__ VT, half_t* __restrict__ O)
{
    __shared__ half_t sK[2][128 * 64];   // 32 KB
    __shared__ half_t sVT[64 * 128];     // 16 KB
    __shared__ half_t sP[8][16 * 128];   // 32 KB
    const int tid = threadIdx.x, wid = tid >> 6, lane = tid & 63;
    const int lm = lane & 15, lg = lane >> 4;
    const int flat = blockIdx.x + (blockIdx.y << 4);
    const int wg = (flat & 7) * 64 + (flat >> 3);
    const int p = wg & 15, bh = wg >> 4;
    const int b = bh >> 4, hh = bh & 15;
    const size_t base = (size_t)bh * (2048 * 64);

    const int qt = (wid < 4) ? p : (31 - p);
    const int q0 = qt * 64 + (wid & 3) * 16;
    const int nTs = (qt + 2) >> 1;          // wave's causal tile count
    const int nTL = (33 - p) >> 1;          // block's staged tile count

    // staging (512 threads: 2 gld16 each for K and for V per tile)
    const int krow = tid >> 3;                        // 0..63
    const int kcsw = ((tid & 7) ^ (krow & 7)) << 4;
    const int vrow = tid >> 4;                        // 0..31
    const int vcsw = ((tid & 15) ^ (vrow & 15)) << 4;
    const char* gK = (const char*)(K + base);
    const char* gV = (const char*)(VT + base);
    half_t* sPw = sP[wid];

    f16x8 vone;
#pragma unroll
    for (int j = 0; j < 8; j++) vone[j] = (half_t)1.f;

    f16x8 bQ[2];
#pragma unroll
    for (int ki = 0; ki < 2; ki++)
        bQ[ki] = *(const f16x8*)(Q + base + (size_t)(q0 + lm) * 64 + ki * 32 + lg * 8);

    fx4 oacc[4] = {};
    fx4 lacc = {};

    // prologue: K(0) -> sK[0], V(0) -> sVT
    {
        char* lK = (char*)sK[0] + tid * 16;
        char* lV = (char*)sVT + tid * 16;
#pragma unroll
        for (int i = 0; i < 2; i++)
            gld16(gK + (size_t)(i * 64 + krow) * 128 + kcsw, lK + i * 8192);
#pragma unroll
        for (int i = 0; i < 2; i++)
            gld16(gV + (size_t)(i * 32 + vrow) * 4096 + vcsw, lV + i * 8192);
    }
    __syncthreads();

    for (int t = 0; t < nTL; t++) {
        const int cur = t & 1;
        // K(t+1) -> other buffer (in flight across this tile's compute)
        if (t + 1 < nTL) {
            const int kv1 = (t + 1) * 128;
            char* lK = (char*)sK[cur ^ 1] + tid * 16;
#pragma unroll
            for (int i = 0; i < 2; i++)
                gld16(gK + (size_t)(kv1 + i * 64 + krow) * 128 + kcsw, lK + i * 8192);
        }
        const int kv0 = t * 128;
        const bool act = (t < nTs);

        if (act) {
            const half_t* cK = sK[cur];
            fx4 st[8] = {};
#pragma unroll
            for (int ki = 0; ki < 2; ki++) {
#pragma unroll
                for (int mi = 0; mi < 8; mi++) {
                    f16x8 aK = *(const f16x8*)(cK + ((mi * 16 + lm) << 6) +
                                               (((ki * 4 + lg) ^ (lm & 7)) << 3));
                    st[mi] = __builtin_amdgcn_mfma_f32_16x16x32_f16(aK, bQ[ki], st[mi], 0, 0, 0);
                }
            }
            const bool diag = (t == nTs - 1);
            const int qg = q0 + lm;
#pragma unroll
            for (int mi = 0; mi < 8; mi++) {
                f16x4 ev;
#pragma unroll
                for (int r = 0; r < 4; r++) {
                    float e = __expf(st[mi][r]);
                    if (diag && (kv0 + mi * 16 + lg * 4 + r > qg)) e = 0.f;
                    ev[r] = (half_t)e;
                }
                *(f16x4*)(sPw + (lm << 7) +
                          ((((mi * 2 + (lg >> 1)) ^ lm) << 3) | ((lg & 1) << 2))) = ev;
            }
        }
        // B2: V(t) (issued end of t-1) + K(t) staged & visible
        __syncthreads();
        if (act) {
#pragma unroll
            for (int k2 = 0; k2 < 4; k2++) {
                f16x8 aP = *(const f16x8*)(sPw + (lm << 7) + (((k2 * 4 + lg) ^ lm) << 3));
#pragma unroll
                for (int ni = 0; ni < 4; ni++) {
                    f16x8 bV = *(const f16x8*)(sVT + ((ni * 16 + lm) << 7) +
                                               (((k2 * 4 + lg) ^ lm) << 3));
                    oacc[ni] = __builtin_amdgcn_mfma_f32_16x16x32_f16(aP, bV, oacc[ni], 0, 0, 0);
                }
                lacc = __builtin_amdgcn_mfma_f32_16x16x32_f16(aP, vone, lacc, 0, 0, 0);
            }
        }
        // B1: all waves' PV reads of V(t) complete -> safe to overwrite
        __syncthreads();
        if (t + 1 < nTL) {
            const int kv1 = (t + 1) * 128;
            char* lV = (char*)sVT + tid * 16;
#pragma unroll
            for (int i = 0; i < 2; i++)
                gld16(gV + (size_t)(i * 32 + vrow) * 4096 + (size_t)kv1 * 2 + vcsw, lV + i * 8192);
        }
    }

    float inv[4];
#pragma unroll
    for (int r = 0; r < 4; r++) inv[r] = 1.f / lacc[r];
#pragma unroll
    for (int ni = 0; ni < 4; ni++)
#pragma unroll
        for (int r = 0; r < 4; r++) {
            int s = q0 + lg * 4 + r;
            O[((size_t)b * 2048 + s) * 1024 + hh * 64 + ni * 16 + lm] =
                (half_t)(oacc[ni][r] * inv[r]);
        }
}

// ---------------------------------------------------------------------------
// Workspace layout (half_t units, Mi = 1048576):
//   0..1 wq16 | 1..2 wk16 | 2..3 wv16 | 3..4 wo16   (dead after their GEMM)
//   4..8 w116 | 8..12 w316 | 12..16 w216
//   16..20 h16 (attn O) | 20..24 q16 | 24..28 k16 | 28..32 vt16
//   a16 = 16..32 (fused silu(u)*g; q/k/vt/h dead by then)
//   h216 = 32..36
//   O-proj partials  P0@20, P1@24          (q16,k16 dead after attn)
//   down partials    D0@0, D1@4, D2@8, D3@36  (wq..wo, w1, w3 dead)
// Max extent 40 Mi halfs = 80 MiB.
// ---------------------------------------------------------------------------
extern "C" void kernel_launch(void* const* d_in, const int* in_sizes, int n_in,
                              void* d_out, int out_size, void* d_ws, size_t ws_size,
                              hipStream_t stream)
{
    const float* x   = (const float*)d_in[0];
    const float* wq  = (const float*)d_in[1];
    const float* wk  = (const float*)d_in[2];
    const float* wv  = (const float*)d_in[3];
    const float* wo  = (const float*)d_in[4];
    const float* ln1 = (const float*)d_in[5];
    const float* ln2 = (const float*)d_in[6];
    const float* w1  = (const float*)d_in[7];
    const float* w2  = (const float*)d_in[8];
    const float* w3  = (const float*)d_in[9];

    half_t* W = (half_t*)d_ws;
    const size_t Mi = 1048576;
    half_t* wq16 = W;
    half_t* wk16 = W + Mi;
    half_t* wv16 = W + 2 * Mi;
    half_t* wo16 = W + 3 * Mi;
    half_t* w116 = W + 4 * Mi;
    half_t* w316 = W + 8 * Mi;
    half_t* w216 = W + 12 * Mi;
    half_t* h16  = W + 16 * Mi;
    half_t* q16  = W + 20 * Mi;
    half_t* k16  = W + 24 * Mi;
    half_t* vt16 = W + 28 * Mi;
    half_t* a16  = W + 16 * Mi;
    half_t* h216 = W + 32 * Mi;
    half_t* P0   = W + 20 * Mi;
    half_t* P1   = W + 24 * Mi;
    half_t* D0   = W;
    half_t* D1   = W + 4 * Mi;
    half_t* D2   = W + 8 * Mi;
    half_t* D3   = W + 36 * Mi;

    CastArgs ca;
    ca.a[0] = { wq, wq16, 262144 };
    ca.a[1] = { wk, wk16, 262144 };
    ca.a[2] = { wv, wv16, 262144 };
    ca.a[3] = { wo, wo16, 262144 };
    ca.a[4] = { w1, w116, 1048576 };
    ca.a[5] = { w2, w216, 1048576 };
    ca.a[6] = { w3, w316, 1048576 };

    // casts (y<7) + rmsnorm(x) (y==7) in one launch
    cast_rms_k<<<dim3(4096, 8), 256, 0, stream>>>(ca, x, ln1, h16);
    // QKV (128^2 tiles, 2 blk/CU) with fused RoPE (z=0,1) / V^T scatter (z=2)
    gemm_bt<1><<<dim3(32, 8, 3), 256, 0, stream>>>(h16, wq16, wk16, wv16,
                                                   q16, k16, vt16, nullptr,
                                                   4096, 1024, 1024);
    attn_k<<<dim3(16, 32), 512, 0, stream>>>(q16, k16, vt16, h16);
    // O-proj partials (split-K=2)
    gemm_bt<4><<<dim3(32, 8, 2), 256, 0, stream>>>(h16, wo16, nullptr, nullptr,
                                                   P0, P1, nullptr, nullptr,
                                                   4096, 1024, 1024);
    // d_out = x + P0 + P1 ; h216 = rmsnorm(d_out)*ln2   (fused)
    addnorm_k<<<dim3(1024), 256, 0, stream>>>(x, P0, P1, ln2,
                                              (float*)d_out, h216);
    // fused SwiGLU up+gate: a16 = silu(h216·w1^T)*(h216·w3^T)
    gemm_dual9<<<dim3(16, 32), 512, 0, stream>>>(h216, w116, w316, a16,
                                                 4096, 4096, 1024);
    // down-proj partials (split-K=4), then d_out += sum(D)
    gemm_bt<4><<<dim3(32, 8, 4), 256, 0, stream>>>(a16, w216, nullptr, nullptr,
                                                   D0, D1, D2, D3,
                                                   4096, 1024, 4096);
    reduce4_k<<<dim3(4096), 256, 0, stream>>>(D0, D1, D2, D3, (float*)d_out, 1048576);
    (void)in_sizes; (void)n_in; (void)out_size; (void)ws_size;
}

// Round 8
// 371.045 us; speedup vs baseline: 1.0040x; 1.0040x over previous
//
#include <hip/hip_runtime.h>

typedef _Float16 half_t;
typedef _Float16 f16x8 __attribute__((ext_vector_type(8)));
typedef _Float16 f16x4 __attribute__((ext_vector_type(4)));
typedef _Float16 f16x2 __attribute__((ext_vector_type(2)));
typedef float fx4 __attribute__((ext_vector_type(4)));

typedef __attribute__((address_space(1))) const unsigned int as1_cuint;
typedef __attribute__((address_space(3))) unsigned int as3_uint;

__device__ __forceinline__ void gld16(const void* g, void* l) {
    __builtin_amdgcn_global_load_lds((as1_cuint*)g, (as3_uint*)l, 16, 0, 0);
}

// ---------------------------------------------------------------------------
// GEMM: C[m][n] = sum_k A[m][k] * B[n][k]   (B row-major [N][K], i.e. B^T)
// 128x128 tile, K-step 32, 4 waves each computing a 64x64 quadrant.
// Best measured structure for the N=1024 / moderate-K call sites (R13).
// LDS swizzle: LDS slot (row,c) holds global chunk c ^ ((row>>1)&3).
// MODE 1: QKV epilogue: z=0,1 -> RoPE fused (pair via __shfl_xor lane^1,
//         angle via __sincosf; Q scaled 0.125); z=2 -> V^T [b,h,dk,s].
// MODE 4: split-K over blockIdx.z; fp16 partial store.
// ---------------------------------------------------------------------------
template<int MODE>
__global__ __launch_bounds__(256, 2)
void gemm_bt(const half_t* __restrict__ A,
             const half_t* __restrict__ B0, const half_t* __restrict__ B1,
             const half_t* __restrict__ B2,
             half_t* o0, half_t* o1, half_t* o2, half_t* o3,
             int M, int N, int K)
{
    __shared__ half_t sA[128 * 32];
    __shared__ half_t sB[128 * 32];
    const int tid = threadIdx.x;
    const int wid = tid >> 6, lane = tid & 63;
    const int lm = lane & 15, lg = lane >> 4;
    const int wr = wid >> 1, wc = wid & 1;
    const int m0 = blockIdx.x * 128, n0 = blockIdx.y * 128;

    const half_t* Bp = B0;
    half_t* outb = o0;
    if (MODE == 1) {
        if (blockIdx.z == 1) { Bp = B1; outb = o1; }
        else if (blockIdx.z == 2) { Bp = B2; outb = o2; }
    }
    if (MODE == 4) {
        if (blockIdx.z == 1) outb = o1;
        else if (blockIdx.z == 2) outb = o2;
        else if (blockIdx.z == 3) outb = o3;
    }

    int Keff = K, koff = 0;
    if (MODE == 4) { Keff = K / gridDim.z; koff = blockIdx.z * Keff; }

    const int srow = tid >> 2;
    const int scolb = ((tid & 3) ^ ((srow >> 1) & 3)) << 4;   // swizzled source chunk
    const char* gA = (const char*)(A + (size_t)(m0 + srow) * K + koff) + scolb;
    const char* gB = (const char*)(Bp + (size_t)(n0 + srow) * K + koff) + scolb;
    const size_t rstep = (size_t)64 * K * sizeof(half_t);
    char* lA = (char*)sA + tid * 16;
    char* lB = (char*)sB + tid * 16;

    const int ksw = (lm >> 1) & 3;                            // read-side key

    fx4 acc[4][4] = {};

    for (int kt = 0; kt < Keff; kt += 32) {
        gld16(gA, lA);
        gld16(gA + rstep, lA + 4096);
        gld16(gB, lB);
        gld16(gB + rstep, lB + 4096);
        gA += 64; gB += 64;
        __syncthreads();
        f16x8 aF[4], bF[4];
#pragma unroll
        for (int mi = 0; mi < 4; mi++)
            aF[mi] = *(const f16x8*)(sA + (wr * 64 + mi * 16 + lm) * 32 + (lg ^ ksw) * 8);
#pragma unroll
        for (int ni = 0; ni < 4; ni++)
            bF[ni] = *(const f16x8*)(sB + (wc * 64 + ni * 16 + lm) * 32 + (lg ^ ksw) * 8);
#pragma unroll
        for (int mi = 0; mi < 4; mi++)
#pragma unroll
            for (int ni = 0; ni < 4; ni++)
                acc[mi][ni] = __builtin_amdgcn_mfma_f32_16x16x32_f16(aF[mi], bF[ni], acc[mi][ni], 0, 0, 0);
        __syncthreads();
    }

#pragma unroll
    for (int mi = 0; mi < 4; mi++) {
#pragma unroll
        for (int ni = 0; ni < 4; ni++) {
#pragma unroll
            for (int r = 0; r < 4; r++) {
                int m = m0 + wr * 64 + mi * 16 + lg * 4 + r;
                int n = n0 + wc * 64 + ni * 16 + lm;
                float v = acc[mi][ni][r];
                size_t idx = (size_t)m * N + n;
                if (MODE == 1) {
                    int b = m >> 11, s = m & 2047, hh = n >> 6, dk = n & 63;
                    if (blockIdx.z == 2) {
                        outb[((size_t)(b * 16 + hh) * 64 + dk) * 2048 + s] = (half_t)v;
                    } else {
                        // fused RoPE: pair (dk even, dk odd) in lanes (lm, lm^1)
                        float pv = __shfl_xor(v, 1);
                        float f = __expf((float)(dk >> 1) * -0.28782313662f);
                        float c, sn;
                        __sincosf((float)s * f, &sn, &c);
                        float xe = (lm & 1) ? pv : v;
                        float xo = (lm & 1) ? v : pv;
                        float rv = (lm & 1) ? (sn * xe + c * xo) : (c * xe - sn * xo);
                        if (blockIdx.z == 0) rv *= 0.125f;
                        outb[((size_t)(b * 16 + hh) * 2048 + s) * 64 + dk] = (half_t)rv;
                    }
                } else {
                    outb[idx] = (half_t)v;     // plain / partial, coalesced
                }
            }
        }
    }
}

// ---------------------------------------------------------------------------
// 256-wide pipeline machinery for the SwiGLU dual GEMM (R10-R12, measured
// 84-90us vs 102us for the 2-phase version).  See KT256 comments.
// ---------------------------------------------------------------------------
#define L256(buf, half, sec) (lbase + (buf) * 65536 + (half) * 16384 + (sec) * 8192)

#define KT256(CUR)                                                            \
  {                                                                           \
    const int BO = (CUR) * 65536;                                             \
    const int st1 = (t < nt - 1), st2 = (t < nt - 2);                         \
    const int s1 = (t + 1) * 128, s2 = (t + 2) * 128;                         \
    f16x8 aLo[4][2], aHi[4][2], bA[2][2], bB[2][2];                           \
    /* ---- phase 1: (m-lo, n-lo) ---- */                                     \
    _Pragma("unroll") for (int mi = 0; mi < 4; mi++) {                        \
        aLo[mi][0] = *(const f16x8*)(aBase + BO + mi * 2048 + swz0);          \
        aLo[mi][1] = *(const f16x8*)(aBase + BO + mi * 2048 + swz1);          \
    }                                                                         \
    _Pragma("unroll") for (int ni = 0; ni < 2; ni++) {                        \
        bA[ni][0] = *(const f16x8*)(bBase + BO + ni * 2048 + swz0);           \
        bA[ni][1] = *(const f16x8*)(bBase + BO + ni * 2048 + swz1);           \
    }                                                                         \
    if (st1) { gld16(pB10 + s1, L256(1 - (CUR), 3, 0));                       \
               gld16(pB1h + s1, L256(1 - (CUR), 3, 1)); }                     \
    asm volatile("s_waitcnt lgkmcnt(8)" ::: "memory");                        \
    __builtin_amdgcn_s_barrier();                                             \
    asm volatile("s_waitcnt lgkmcnt(0)" ::: "memory");                        \
    __builtin_amdgcn_sched_barrier(0);                                        \
    __builtin_amdgcn_s_setprio(1);                                            \
    _Pragma("unroll") for (int kk = 0; kk < 2; kk++)                          \
      _Pragma("unroll") for (int mi = 0; mi < 4; mi++)                        \
        _Pragma("unroll") for (int ni = 0; ni < 2; ni++)                      \
          acc[mi][ni] = __builtin_amdgcn_mfma_f32_16x16x32_f16(aLo[mi][kk], bA[ni][kk], acc[mi][ni], 0, 0, 0); \
    __builtin_amdgcn_s_setprio(0);                                            \
    __builtin_amdgcn_s_barrier();                                             \
    /* ---- phase 2: (m-lo, n-hi) ---- */                                     \
    _Pragma("unroll") for (int ni = 0; ni < 2; ni++) {                        \
        bB[ni][0] = *(const f16x8*)(bBase + BO + (2 + ni) * 2048 + swz0);     \
        bB[ni][1] = *(const f16x8*)(bBase + BO + (2 + ni) * 2048 + swz1);     \
    }                                                                         \
    if (st2) { gld16(pA00 + s2, L256(CUR, 0, 0)); }                           \
    __builtin_amdgcn_s_barrier();                                             \
    asm volatile("s_waitcnt lgkmcnt(0)" ::: "memory");                        \
    __builtin_amdgcn_sched_barrier(0);                                        \
    __builtin_amdgcn_s_setprio(1);                                            \
    _Pragma("unroll") for (int kk = 0; kk < 2; kk++)                          \
      _Pragma("unroll") for (int mi = 0; mi < 4; mi++)                        \
        _Pragma("unroll") for (int ni = 0; ni < 2; ni++)                      \
          acc[mi][2 + ni] = __builtin_amdgcn_mfma_f32_16x16x32_f16(aLo[mi][kk], bB[ni][kk], acc[mi][2 + ni], 0, 0, 0); \
    __builtin_amdgcn_s_setprio(0);                                            \
    __builtin_amdgcn_s_barrier();                                             \
    /* ---- phase 3: (m-hi, n-hi) ---- */                                     \
    _Pragma("unroll") for (int mi = 0; mi < 4; mi++) {                        \
        aHi[mi][0] = *(const f16x8*)(aBase + BO + (4 + mi) * 2048 + swz0);    \
        aHi[mi][1] = *(const f16x8*)(aBase + BO + (4 + mi) * 2048 + swz1);    \
    }                                                                         \
    if (st2) { gld16(pB00 + s2, L256(CUR, 2, 0));                             \
               gld16(pB0h + s2, L256(CUR, 2, 1)); }                           \
    __builtin_amdgcn_s_barrier();                                             \
    asm volatile("s_waitcnt lgkmcnt(0)" ::: "memory");                        \
    __builtin_amdgcn_sched_barrier(0);                                        \
    __builtin_amdgcn_s_setprio(1);                                            \
    _Pragma("unroll") for (int kk = 0; kk < 2; kk++)                          \
      _Pragma("unroll") for (int mi = 0; mi < 4; mi++)                        \
        _Pragma("unroll") for (int ni = 0; ni < 2; ni++)                      \
          acc[4 + mi][2 + ni] = __builtin_amdgcn_mfma_f32_16x16x32_f16(aHi[mi][kk], bB[ni][kk], acc[4 + mi][2 + ni], 0, 0, 0); \
    __builtin_amdgcn_s_setprio(0);                                            \
    __builtin_amdgcn_s_barrier();                                             \
    /* ---- phase 4: (m-hi, n-lo) ---- */                                     \
    if (st2) { gld16(pA0h + s2, L256(CUR, 0, 1));                             \
               gld16(pA10 + s2, L256(CUR, 1, 0));                             \
               gld16(pA1h + s2, L256(CUR, 1, 1)); }                           \
    __builtin_amdgcn_s_barrier();                                             \
    __builtin_amdgcn_sched_barrier(0);                                        \
    __builtin_amdgcn_s_setprio(1);                                            \
    _Pragma("unroll") for (int kk = 0; kk < 2; kk++)                          \
      _Pragma("unroll") for (int mi = 0; mi < 4; mi++)                        \
        _Pragma("unroll") for (int ni = 0; ni < 2; ni++)                      \
          acc[4 + mi][ni] = __builtin_amdgcn_mfma_f32_16x16x32_f16(aHi[mi][kk], bA[ni][kk], acc[4 + mi][ni], 0, 0, 0); \
    __builtin_amdgcn_s_setprio(0);                                            \
    if (t < nt - 2)       { asm volatile("s_waitcnt vmcnt(6)" ::: "memory"); }\
    else if (t == nt - 2) { asm volatile("s_waitcnt vmcnt(0)" ::: "memory"); }\
    __builtin_amdgcn_s_barrier();                                             \
  }

#define PRO256()                                                              \
    gld16(pA00, L256(0, 0, 0));                                               \
    gld16(pB00, L256(0, 2, 0)); gld16(pB0h, L256(0, 2, 1));                   \
    gld16(pA0h, L256(0, 0, 1)); gld16(pA10, L256(0, 1, 0)); gld16(pA1h, L256(0, 1, 1)); \
    gld16(pB10, L256(0, 3, 0)); gld16(pB1h, L256(0, 3, 1));                   \
    gld16(pA00 + 128, L256(1, 0, 0));                                         \
    gld16(pB00 + 128, L256(1, 2, 0)); gld16(pB0h + 128, L256(1, 2, 1));       \
    gld16(pA0h + 128, L256(1, 0, 1)); gld16(pA10 + 128, L256(1, 1, 0)); gld16(pA1h + 128, L256(1, 1, 1)); \
    asm volatile("s_waitcnt vmcnt(6)" ::: "memory");                          \
    __builtin_amdgcn_s_barrier();

// ---------------------------------------------------------------------------
// Fused SwiGLU up+gate GEMM (256x128 half-tile pipeline + XCD swizzle).
// One 256x256 GEMM: B panel = [128 rows of w1 | 128 rows of w3]; wc<2 -> U,
// wc>=2 -> G.  Epilogue: G-waves publish acc via LDS, U-waves fuse silu(u)*g.
// ---------------------------------------------------------------------------
__global__ __launch_bounds__(512, 2)
void gemm_dual9(const half_t* __restrict__ A,
                const half_t* __restrict__ B1, const half_t* __restrict__ B2,
                half_t* __restrict__ out, int M, int N, int K)
{
    __shared__ half_t smem[65536];   // 128 KiB
    const int tid = threadIdx.x;
    const int wid = tid >> 6, lane = tid & 63;
    const int lm = lane & 15, lg = lane >> 4;
    const int wr = wid >> 2, wc = wid & 3;
    // XCD swizzle (grid 16x32 = 512, 512%8==0 -> simple bijection)
    const int flat = blockIdx.x + (blockIdx.y << 4);
    const int wg = (flat & 7) * 64 + (flat >> 3);
    const int m0 = (wg & 15) * 256, n0 = (wg >> 4) * 128;

    const size_t KB = (size_t)K * 2;
    const int srow = tid >> 3;
    const int schunk = (tid & 7) ^ (srow & 7);
    const char* pA  = (const char*)A  + (size_t)(m0 + srow) * KB + schunk * 16;
    const char* pB0 = (const char*)B1 + (size_t)(n0 + srow) * KB + schunk * 16;
    const char* pB1 = (const char*)B2 + (size_t)(n0 + srow) * KB + schunk * 16;
    const char* pA00 = pA;
    const char* pA0h = pA + 64 * KB;
    const char* pA10 = pA + 128 * KB;
    const char* pA1h = pA + 192 * KB;
    const char* pB00 = pB0;
    const char* pB0h = pB0 + 64 * KB;
    const char* pB10 = pB1;
    const char* pB1h = pB1 + 64 * KB;
    const int nt = 16;

    char* const lbase = (char*)smem + tid * 16;

    const int swz0 = ((lg ^ (lm & 7)) << 4);
    const int swz1 = (((4 + lg) ^ (lm & 7)) << 4);
    const char* aBase = (const char*)smem + wr * 16384 + lm * 128;
    const char* bBase = (const char*)smem + (2 + (wc >> 1)) * 16384 + (wc & 1) * 8192 + lm * 128;

    PRO256()

    fx4 acc[8][4] = {};

#pragma unroll 1
    for (int tt = 0; tt < 16; tt += 2) {
        { const int t = tt;     KT256(0) }
        { const int t = tt + 1; KT256(1) }
    }

    // ---- epilogue: G-waves publish frags via LDS, U-waves fuse silu(u)*g
    float* gb = (float*)smem;
    if (wc >= 2) {
        const int gw = wr * 2 + (wc - 2);
#pragma unroll
        for (int mi = 0; mi < 8; mi++)
#pragma unroll
            for (int ni = 0; ni < 4; ni++)
                *(fx4*)((char*)gb + ((((gw * 8 + mi) * 4 + ni) * 64 + lane) << 4)) = acc[mi][ni];
    }
    __syncthreads();
    if (wc < 2) {
        const int gw = wr * 2 + wc;
#pragma unroll
        for (int mi = 0; mi < 8; mi++)
#pragma unroll
            for (int ni = 0; ni < 4; ni++) {
                fx4 gv = *(const fx4*)((const char*)gb + ((((gw * 8 + mi) * 4 + ni) * 64 + lane) << 4));
#pragma unroll
                for (int r = 0; r < 4; r++) {
                    int m = m0 + wr * 128 + mi * 16 + lg * 4 + r;
                    int n = n0 + wc * 64 + ni * 16 + lm;
                    float u = acc[mi][ni][r], g = gv[r];
                    out[(size_t)m * N + n] = (half_t)(u / (1.f + __expf(-u)) * g);
                }
            }
    }
}

// ---------------------------------------------------------------------------
// Fused O-proj combine + residual + RMSNorm (split-K=2 partials):
//   t = x + p0 + p1;  outF = t;  outH = rmsnorm(t)*w  (fp16)
// ---------------------------------------------------------------------------
__global__ __launch_bounds__(256, 4)
void addnorm_k(const float* __restrict__ x,
               const half_t* __restrict__ p0, const half_t* __restrict__ p1,
               const float* __restrict__ w,
               float* __restrict__ outF, half_t* __restrict__ outH)
{
    int row = blockIdx.x * 4 + (threadIdx.x >> 6);
    int lane = threadIdx.x & 63;
    const float4* xr = (const float4*)(x + (size_t)row * 1024);
    const f16x4* p0r = (const f16x4*)(p0 + (size_t)row * 1024);
    const f16x4* p1r = (const f16x4*)(p1 + (size_t)row * 1024);
    float4 v[4];
    float s = 0.f;
#pragma unroll
    for (int i = 0; i < 4; i++) {
        float4 xv = xr[lane + 64 * i];
        f16x4 a0 = p0r[lane + 64 * i];
        f16x4 a1 = p1r[lane + 64 * i];
        v[i].x = xv.x + (float)a0[0] + (float)a1[0];
        v[i].y = xv.y + (float)a0[1] + (float)a1[1];
        v[i].z = xv.z + (float)a0[2] + (float)a1[2];
        v[i].w = xv.w + (float)a0[3] + (float)a1[3];
        s += v[i].x * v[i].x + v[i].y * v[i].y + v[i].z * v[i].z + v[i].w * v[i].w;
    }
#pragma unroll
    for (int o = 32; o > 0; o >>= 1) s += __shfl_xor(s, o);
    float inv = rsqrtf(s * (1.f / 1024.f) + 1e-5f);
    const float4* w4 = (const float4*)w;
    float4* oF = (float4*)(outF + (size_t)row * 1024);
    f16x4* oH = (f16x4*)(outH + (size_t)row * 1024);
#pragma unroll
    for (int i = 0; i < 4; i++) {
        oF[lane + 64 * i] = v[i];
        float4 wv = w4[lane + 64 * i];
        f16x4 ov = { (half_t)(v[i].x * inv * wv.x), (half_t)(v[i].y * inv * wv.y),
                     (half_t)(v[i].z * inv * wv.z), (half_t)(v[i].w * inv * wv.w) };
        oH[lane + 64 * i] = ov;
    }
}

// ---------------------------------------------------------------------------
// Split-K=4 combine: out = out + p0 + p1 + p2 + p3
// ---------------------------------------------------------------------------
__global__ __launch_bounds__(256, 8)
void reduce4_k(const half_t* __restrict__ p0, const half_t* __restrict__ p1,
               const half_t* __restrict__ p2, const half_t* __restrict__ p3,
               float* __restrict__ out, int n4)
{
    int i = blockIdx.x * 256 + threadIdx.x;
    if (i >= n4) return;
    float4 b = ((const float4*)out)[i];
    f16x4 a0 = ((const f16x4*)p0)[i];
    f16x4 a1 = ((const f16x4*)p1)[i];
    f16x4 a2 = ((const f16x4*)p2)[i];
    f16x4 a3 = ((const f16x4*)p3)[i];
    float4 o = { b.x + (float)a0[0] + (float)a1[0] + (float)a2[0] + (float)a3[0],
                 b.y + (float)a0[1] + (float)a1[1] + (float)a2[1] + (float)a3[1],
                 b.z + (float)a0[2] + (float)a1[2] + (float)a2[2] + (float)a3[2],
                 b.w + (float)a0[3] + (float)a1[3] + (float)a2[3] + (float)a3[3] };
    ((float4*)out)[i] = o;
}

// ---------------------------------------------------------------------------
// Fused: cast 7 weight matrices fp32->fp16 (y<7) + RMSNorm of x (y==7)
// ---------------------------------------------------------------------------
struct CastA { const float* s; half_t* d; int n4; };
struct CastArgs { CastA a[7]; };

__global__ __launch_bounds__(256)
void cast_rms_k(CastArgs ca, const float* __restrict__ x,
                const float* __restrict__ w, half_t* __restrict__ out)
{
    if (blockIdx.y < 7) {
        CastA a = ca.a[blockIdx.y];
        int i = blockIdx.x * 256 + threadIdx.x;
        if (i >= a.n4) return;
        float4 v = ((const float4*)a.s)[i];
        ((f16x4*)a.d)[i] = (f16x4){ (half_t)v.x, (half_t)v.y, (half_t)v.z, (half_t)v.w };
        return;
    }
    if (blockIdx.x >= 1024) return;
    int row = blockIdx.x * 4 + (threadIdx.x >> 6);
    int lane = threadIdx.x & 63;
    const float4* xr = (const float4*)(x + (size_t)row * 1024);
    float4 v[4];
    float s = 0.f;
#pragma unroll
    for (int i = 0; i < 4; i++) {
        v[i] = xr[lane + 64 * i];
        s += v[i].x * v[i].x + v[i].y * v[i].y + v[i].z * v[i].z + v[i].w * v[i].w;
    }
#pragma unroll
    for (int o = 32; o > 0; o >>= 1) s += __shfl_xor(s, o);
    float inv = rsqrtf(s * (1.f / 1024.f) + 1e-5f);
    const float4* w4 = (const float4*)w;
    f16x4* o4 = (f16x4*)(out + (size_t)row * 1024);
#pragma unroll
    for (int i = 0; i < 4; i++) {
        float4 wv = w4[lane + 64 * i];
        f16x4 ov = { (half_t)(v[i].x * inv * wv.x), (half_t)(v[i].y * inv * wv.y),
                     (half_t)(v[i].z * inv * wv.z), (half_t)(v[i].w * inv * wv.w) };
        o4[lane + 64 * i] = ov;
    }
}

// ---------------------------------------------------------------------------
// Causal flash attention, balanced + shuffle-free (R5 best-measured config;
// R6 dbuf and R7 paired-tile variants measured neutral / -9.5us).
// Q,K: [b,h,s,64] (RoPE pre-applied, Q pre-scaled).  VT: [b,h,dk,s].
// XCD swizzle: each XCD owns 4 complete heads -> K/V (2 MB) L2-resident.
// ---------------------------------------------------------------------------
__global__ __launch_bounds__(256, 2)
void attn_k(const half_t* __restrict__ Q, const half_t* __restrict__ K,
            const half_t* __restrict__ VT, half_t* __restrict__ O)
{
    __shared__ half_t sK[128 * 64];
    __shared__ half_t sVT[64 * 128];
    __shared__ half_t sP[4][16 * 128];
    const int tid = threadIdx.x, wid = tid >> 6, lane = tid & 63;
    const int lm = lane & 15, lg = lane >> 4;
    const int flat = blockIdx.x + (blockIdx.y << 4);
    const int wg = (flat & 7) * 64 + (flat >> 3);
    const int p = wg & 15, bh = wg >> 4;
    const int b = bh >> 4, hh = bh & 15;
    const size_t base = (size_t)bh * (2048 * 64);

    const int krow = tid >> 3;
    const int kcsw = ((tid & 7) ^ (krow & 7)) << 4;
    const int vrow = tid >> 4;
    const int vcsw = ((tid & 15) ^ (vrow & 15)) << 4;
    const char* gK = (const char*)(K + base);
    const char* gV = (const char*)(VT + base);
    char* lK = (char*)sK + tid * 16;
    char* lV = (char*)sVT + tid * 16;
    half_t* sPw = sP[wid];

    f16x8 vone;
#pragma unroll
    for (int j = 0; j < 8; j++) vone[j] = (half_t)1.f;

    for (int ph = 0; ph < 2; ph++) {
        const int qt = ph ? (31 - p) : p;
        const int q0 = qt * 64 + wid * 16;
        const int nT = (qt + 2) >> 1;

        f16x8 bQ[2];
#pragma unroll
        for (int ki = 0; ki < 2; ki++)
            bQ[ki] = *(const f16x8*)(Q + base + (size_t)(q0 + lm) * 64 + ki * 32 + lg * 8);

        fx4 oacc[4] = {};
        fx4 lacc = {};

        for (int t = 0; t < nT; t++) {
            const int kv0 = t * 128;
#pragma unroll
            for (int i = 0; i < 4; i++)
                gld16(gK + (size_t)(kv0 + i * 32 + krow) * 128 + kcsw, lK + i * 4096);
#pragma unroll
            for (int i = 0; i < 4; i++)
                gld16(gV + (size_t)(i * 16 + vrow) * 4096 + (size_t)kv0 * 2 + vcsw, lV + i * 4096);
            __syncthreads();

            fx4 st[8] = {};
#pragma unroll
            for (int ki = 0; ki < 2; ki++) {
#pragma unroll
                for (int mi = 0; mi < 8; mi++) {
                    f16x8 aK = *(const f16x8*)(sK + ((mi * 16 + lm) << 6) +
                                               (((ki * 4 + lg) ^ (lm & 7)) << 3));
                    st[mi] = __builtin_amdgcn_mfma_f32_16x16x32_f16(aK, bQ[ki], st[mi], 0, 0, 0);
                }
            }

            const bool diag = (t == nT - 1);
            const int qg = q0 + lm;
#pragma unroll
            for (int mi = 0; mi < 8; mi++) {
                f16x4 ev;
#pragma unroll
                for (int r = 0; r < 4; r++) {
                    float e = __expf(st[mi][r]);
                    if (diag && (kv0 + mi * 16 + lg * 4 + r > qg)) e = 0.f;
                    ev[r] = (half_t)e;
                }
                *(f16x4*)(sPw + (lm << 7) +
                          ((((mi * 2 + (lg >> 1)) ^ lm) << 3) | ((lg & 1) << 2))) = ev;
            }

#pragma unroll
            for (int k2 = 0; k2 < 4; k2++) {
                f16x8 aP = *(const f16x8*)(sPw + (lm << 7) + (((k2 * 4 + lg) ^ lm) << 3));
#pragma unroll
                for (int ni = 0; ni < 4; ni++) {
                    f16x8 bV = *(const f16x8*)(sVT + ((ni * 16 + lm) << 7) +
                                               (((k2 * 4 + lg) ^ lm) << 3));
                    oacc[ni] = __builtin_amdgcn_mfma_f32_16x16x32_f16(aP, bV, oacc[ni], 0, 0, 0);
                }
                lacc = __builtin_amdgcn_mfma_f32_16x16x32_f16(aP, vone, lacc, 0, 0, 0);
            }
            __syncthreads();
        }

        float inv[4];
#pragma unroll
        for (int r = 0; r < 4; r++) inv[r] = 1.f / lacc[r];
#pragma unroll
        for (int ni = 0; ni < 4; ni++)
#pragma unroll
            for (int r = 0; r < 4; r++) {
                int s = q0 + lg * 4 + r;
                O[((size_t)b * 2048 + s) * 1024 + hh * 64 + ni * 16 + lm] =
                    (half_t)(oacc[ni][r] * inv[r]);
            }
    }
}

// ---------------------------------------------------------------------------
// Workspace layout (half_t units, Mi = 1048576):
//   0..1 wq16 | 1..2 wk16 | 2..3 wv16 | 3..4 wo16   (dead after their GEMM)
//   4..8 w116 | 8..12 w316 | 12..16 w216
//   16..20 h16 (attn O) | 20..24 q16 | 24..28 k16 | 28..32 vt16
//   a16 = 16..32 (fused silu(u)*g; q/k/vt/h dead by then)
//   h216 = 32..36
//   O-proj partials  P0@20, P1@24          (q16,k16 dead after attn)
//   down partials    D0@0, D1@4, D2@8, D3@36  (wq..wo, w1, w3 dead)
// Max extent 40 Mi halfs = 80 MiB.
// ---------------------------------------------------------------------------
extern "C" void kernel_launch(void* const* d_in, const int* in_sizes, int n_in,
                              void* d_out, int out_size, void* d_ws, size_t ws_size,
                              hipStream_t stream)
{
    const float* x   = (const float*)d_in[0];
    const float* wq  = (const float*)d_in[1];
    const float* wk  = (const float*)d_in[2];
    const float* wv  = (const float*)d_in[3];
    const float* wo  = (const float*)d_in[4];
    const float* ln1 = (const float*)d_in[5];
    const float* ln2 = (const float*)d_in[6];
    const float* w1  = (const float*)d_in[7];
    const float* w2  = (const float*)d_in[8];
    const float* w3  = (const float*)d_in[9];

    half_t* W = (half_t*)d_ws;
    const size_t Mi = 1048576;
    half_t* wq16 = W;
    half_t* wk16 = W + Mi;
    half_t* wv16 = W + 2 * Mi;
    half_t* wo16 = W + 3 * Mi;
    half_t* w116 = W + 4 * Mi;
    half_t* w316 = W + 8 * Mi;
    half_t* w216 = W + 12 * Mi;
    half_t* h16  = W + 16 * Mi;
    half_t* q16  = W + 20 * Mi;
    half_t* k16  = W + 24 * Mi;
    half_t* vt16 = W + 28 * Mi;
    half_t* a16  = W + 16 * Mi;
    half_t* h216 = W + 32 * Mi;
    half_t* P0   = W + 20 * Mi;
    half_t* P1   = W + 24 * Mi;
    half_t* D0   = W;
    half_t* D1   = W + 4 * Mi;
    half_t* D2   = W + 8 * Mi;
    half_t* D3   = W + 36 * Mi;

    CastArgs ca;
    ca.a[0] = { wq, wq16, 262144 };
    ca.a[1] = { wk, wk16, 262144 };
    ca.a[2] = { wv, wv16, 262144 };
    ca.a[3] = { wo, wo16, 262144 };
    ca.a[4] = { w1, w116, 1048576 };
    ca.a[5] = { w2, w216, 1048576 };
    ca.a[6] = { w3, w316, 1048576 };

    // casts (y<7) + rmsnorm(x) (y==7) in one launch
    cast_rms_k<<<dim3(4096, 8), 256, 0, stream>>>(ca, x, ln1, h16);
    // QKV (128^2 tiles, 2 blk/CU) with fused RoPE (z=0,1) / V^T scatter (z=2)
    gemm_bt<1><<<dim3(32, 8, 3), 256, 0, stream>>>(h16, wq16, wk16, wv16,
                                                   q16, k16, vt16, nullptr,
                                                   4096, 1024, 1024);
    attn_k<<<dim3(16, 32), 256, 0, stream>>>(q16, k16, vt16, h16);
    // O-proj partials (split-K=2)
    gemm_bt<4><<<dim3(32, 8, 2), 256, 0, stream>>>(h16, wo16, nullptr, nullptr,
                                                   P0, P1, nullptr, nullptr,
                                                   4096, 1024, 1024);
    // d_out = x + P0 + P1 ; h216 = rmsnorm(d_out)*ln2   (fused)
    addnorm_k<<<dim3(1024), 256, 0, stream>>>(x, P0, P1, ln2,
                                              (float*)d_out, h216);
    // fused SwiGLU up+gate: a16 = silu(h216·w1^T)*(h216·w3^T)
    gemm_dual9<<<dim3(16, 32), 512, 0, stream>>>(h216, w116, w316, a16,
                                                 4096, 4096, 1024);
    // down-proj partials (split-K=4), then d_out += sum(D)
    gemm_bt<4><<<dim3(32, 8, 4), 256, 0, stream>>>(a16, w216, nullptr, nullptr,
                                                   D0, D1, D2, D3,
                                                   4096, 1024, 4096);
    reduce4_k<<<dim3(4096), 256, 0, stream>>>(D0, D1, D2, D3, (float*)d_out, 1048576);
    (void)in_sizes; (void)n_in; (void)out_size; (void)ws_size;
}

// Round 9
// 355.816 us; speedup vs baseline: 1.0469x; 1.0428x over previous
//
#include <hip/hip_runtime.h>

typedef _Float16 half_t;
typedef _Float16 f16x8 __attribute__((ext_vector_type(8)));
typedef _Float16 f16x4 __attribute__((ext_vector_type(4)));
typedef _Float16 f16x2 __attribute__((ext_vector_type(2)));
typedef float fx4 __attribute__((ext_vector_type(4)));

typedef __attribute__((address_space(1))) const unsigned int as1_cuint;
typedef __attribute__((address_space(3))) unsigned int as3_uint;

__device__ __forceinline__ void gld16(const void* g, void* l) {
    __builtin_amdgcn_global_load_lds((as1_cuint*)g, (as3_uint*)l, 16, 0, 0);
}

// ---------------------------------------------------------------------------
// GEMM: C[m][n] = sum_k A[m][k] * B[n][k]   (B row-major [N][K], i.e. B^T)
// 128x128 tile, K-step 32, 4 waves each computing a 64x64 quadrant.
// Best measured structure for QKV / O-proj call sites (R13).
// LDS swizzle: LDS slot (row,c) holds global chunk c ^ ((row>>1)&3).
// MODE 1: QKV epilogue: z=0,1 -> RoPE fused (pair via __shfl_xor lane^1,
//         angle via __sincosf; Q scaled 0.125); z=2 -> V^T [b,h,dk,s].
// MODE 4: split-K over blockIdx.z; fp16 partial store.
// ---------------------------------------------------------------------------
template<int MODE>
__global__ __launch_bounds__(256, 2)
void gemm_bt(const half_t* __restrict__ A,
             const half_t* __restrict__ B0, const half_t* __restrict__ B1,
             const half_t* __restrict__ B2,
             half_t* o0, half_t* o1, half_t* o2, half_t* o3,
             int M, int N, int K)
{
    __shared__ half_t sA[128 * 32];
    __shared__ half_t sB[128 * 32];
    const int tid = threadIdx.x;
    const int wid = tid >> 6, lane = tid & 63;
    const int lm = lane & 15, lg = lane >> 4;
    const int wr = wid >> 1, wc = wid & 1;
    const int m0 = blockIdx.x * 128, n0 = blockIdx.y * 128;

    const half_t* Bp = B0;
    half_t* outb = o0;
    if (MODE == 1) {
        if (blockIdx.z == 1) { Bp = B1; outb = o1; }
        else if (blockIdx.z == 2) { Bp = B2; outb = o2; }
    }
    if (MODE == 4) {
        if (blockIdx.z == 1) outb = o1;
        else if (blockIdx.z == 2) outb = o2;
        else if (blockIdx.z == 3) outb = o3;
    }

    int Keff = K, koff = 0;
    if (MODE == 4) { Keff = K / gridDim.z; koff = blockIdx.z * Keff; }

    const int srow = tid >> 2;
    const int scolb = ((tid & 3) ^ ((srow >> 1) & 3)) << 4;   // swizzled source chunk
    const char* gA = (const char*)(A + (size_t)(m0 + srow) * K + koff) + scolb;
    const char* gB = (const char*)(Bp + (size_t)(n0 + srow) * K + koff) + scolb;
    const size_t rstep = (size_t)64 * K * sizeof(half_t);
    char* lA = (char*)sA + tid * 16;
    char* lB = (char*)sB + tid * 16;

    const int ksw = (lm >> 1) & 3;                            // read-side key

    fx4 acc[4][4] = {};

    for (int kt = 0; kt < Keff; kt += 32) {
        gld16(gA, lA);
        gld16(gA + rstep, lA + 4096);
        gld16(gB, lB);
        gld16(gB + rstep, lB + 4096);
        gA += 64; gB += 64;
        __syncthreads();
        f16x8 aF[4], bF[4];
#pragma unroll
        for (int mi = 0; mi < 4; mi++)
            aF[mi] = *(const f16x8*)(sA + (wr * 64 + mi * 16 + lm) * 32 + (lg ^ ksw) * 8);
#pragma unroll
        for (int ni = 0; ni < 4; ni++)
            bF[ni] = *(const f16x8*)(sB + (wc * 64 + ni * 16 + lm) * 32 + (lg ^ ksw) * 8);
#pragma unroll
        for (int mi = 0; mi < 4; mi++)
#pragma unroll
            for (int ni = 0; ni < 4; ni++)
                acc[mi][ni] = __builtin_amdgcn_mfma_f32_16x16x32_f16(aF[mi], bF[ni], acc[mi][ni], 0, 0, 0);
        __syncthreads();
    }

#pragma unroll
    for (int mi = 0; mi < 4; mi++) {
#pragma unroll
        for (int ni = 0; ni < 4; ni++) {
#pragma unroll
            for (int r = 0; r < 4; r++) {
                int m = m0 + wr * 64 + mi * 16 + lg * 4 + r;
                int n = n0 + wc * 64 + ni * 16 + lm;
                float v = acc[mi][ni][r];
                size_t idx = (size_t)m * N + n;
                if (MODE == 1) {
                    int b = m >> 11, s = m & 2047, hh = n >> 6, dk = n & 63;
                    if (blockIdx.z == 2) {
                        outb[((size_t)(b * 16 + hh) * 64 + dk) * 2048 + s] = (half_t)v;
                    } else {
                        // fused RoPE: pair (dk even, dk odd) in lanes (lm, lm^1)
                        float pv = __shfl_xor(v, 1);
                        float f = __expf((float)(dk >> 1) * -0.28782313662f);
                        float c, sn;
                        __sincosf((float)s * f, &sn, &c);
                        float xe = (lm & 1) ? pv : v;
                        float xo = (lm & 1) ? v : pv;
                        float rv = (lm & 1) ? (sn * xe + c * xo) : (c * xe - sn * xo);
                        if (blockIdx.z == 0) rv *= 0.125f;
                        outb[((size_t)(b * 16 + hh) * 2048 + s) * 64 + dk] = (half_t)rv;
                    }
                } else {
                    outb[idx] = (half_t)v;     // plain / partial, coalesced
                }
            }
        }
    }
}

// ---------------------------------------------------------------------------
// 256-wide pipeline machinery (R10-R12): 4 phases/K-tile, quadrant rotation,
// staging 2/1/2/3 gld16 per phase, ONE counted vmcnt(6) per K-tile.
// ---------------------------------------------------------------------------
#define L256(buf, half, sec) (lbase + (buf) * 65536 + (half) * 16384 + (sec) * 8192)

#define KT256(CUR)                                                            \
  {                                                                           \
    const int BO = (CUR) * 65536;                                             \
    const int st1 = (t < nt - 1), st2 = (t < nt - 2);                         \
    const int s1 = (t + 1) * 128, s2 = (t + 2) * 128;                         \
    f16x8 aLo[4][2], aHi[4][2], bA[2][2], bB[2][2];                           \
    /* ---- phase 1: (m-lo, n-lo) ---- */                                     \
    _Pragma("unroll") for (int mi = 0; mi < 4; mi++) {                        \
        aLo[mi][0] = *(const f16x8*)(aBase + BO + mi * 2048 + swz0);          \
        aLo[mi][1] = *(const f16x8*)(aBase + BO + mi * 2048 + swz1);          \
    }                                                                         \
    _Pragma("unroll") for (int ni = 0; ni < 2; ni++) {                        \
        bA[ni][0] = *(const f16x8*)(bBase + BO + ni * 2048 + swz0);           \
        bA[ni][1] = *(const f16x8*)(bBase + BO + ni * 2048 + swz1);           \
    }                                                                         \
    if (st1) { gld16(pB10 + s1, L256(1 - (CUR), 3, 0));                       \
               gld16(pB1h + s1, L256(1 - (CUR), 3, 1)); }                     \
    asm volatile("s_waitcnt lgkmcnt(8)" ::: "memory");                        \
    __builtin_amdgcn_s_barrier();                                             \
    asm volatile("s_waitcnt lgkmcnt(0)" ::: "memory");                        \
    __builtin_amdgcn_sched_barrier(0);                                        \
    __builtin_amdgcn_s_setprio(1);                                            \
    _Pragma("unroll") for (int kk = 0; kk < 2; kk++)                          \
      _Pragma("unroll") for (int mi = 0; mi < 4; mi++)                        \
        _Pragma("unroll") for (int ni = 0; ni < 2; ni++)                      \
          acc[mi][ni] = __builtin_amdgcn_mfma_f32_16x16x32_f16(aLo[mi][kk], bA[ni][kk], acc[mi][ni], 0, 0, 0); \
    __builtin_amdgcn_s_setprio(0);                                            \
    __builtin_amdgcn_s_barrier();                                             \
    /* ---- phase 2: (m-lo, n-hi) ---- */                                     \
    _Pragma("unroll") for (int ni = 0; ni < 2; ni++) {                        \
        bB[ni][0] = *(const f16x8*)(bBase + BO + (2 + ni) * 2048 + swz0);     \
        bB[ni][1] = *(const f16x8*)(bBase + BO + (2 + ni) * 2048 + swz1);     \
    }                                                                         \
    if (st2) { gld16(pA00 + s2, L256(CUR, 0, 0)); }                           \
    __builtin_amdgcn_s_barrier();                                             \
    asm volatile("s_waitcnt lgkmcnt(0)" ::: "memory");                        \
    __builtin_amdgcn_sched_barrier(0);                                        \
    __builtin_amdgcn_s_setprio(1);                                            \
    _Pragma("unroll") for (int kk = 0; kk < 2; kk++)                          \
      _Pragma("unroll") for (int mi = 0; mi < 4; mi++)                        \
        _Pragma("unroll") for (int ni = 0; ni < 2; ni++)                      \
          acc[mi][2 + ni] = __builtin_amdgcn_mfma_f32_16x16x32_f16(aLo[mi][kk], bB[ni][kk], acc[mi][2 + ni], 0, 0, 0); \
    __builtin_amdgcn_s_setprio(0);                                            \
    __builtin_amdgcn_s_barrier();                                             \
    /* ---- phase 3: (m-hi, n-hi) ---- */                                     \
    _Pragma("unroll") for (int mi = 0; mi < 4; mi++) {                        \
        aHi[mi][0] = *(const f16x8*)(aBase + BO + (4 + mi) * 2048 + swz0);    \
        aHi[mi][1] = *(const f16x8*)(aBase + BO + (4 + mi) * 2048 + swz1);    \
    }                                                                         \
    if (st2) { gld16(pB00 + s2, L256(CUR, 2, 0));                             \
               gld16(pB0h + s2, L256(CUR, 2, 1)); }                           \
    __builtin_amdgcn_s_barrier();                                             \
    asm volatile("s_waitcnt lgkmcnt(0)" ::: "memory");                        \
    __builtin_amdgcn_sched_barrier(0);                                        \
    __builtin_amdgcn_s_setprio(1);                                            \
    _Pragma("unroll") for (int kk = 0; kk < 2; kk++)                          \
      _Pragma("unroll") for (int mi = 0; mi < 4; mi++)                        \
        _Pragma("unroll") for (int ni = 0; ni < 2; ni++)                      \
          acc[4 + mi][2 + ni] = __builtin_amdgcn_mfma_f32_16x16x32_f16(aHi[mi][kk], bB[ni][kk], acc[4 + mi][2 + ni], 0, 0, 0); \
    __builtin_amdgcn_s_setprio(0);                                            \
    __builtin_amdgcn_s_barrier();                                             \
    /* ---- phase 4: (m-hi, n-lo) ---- */                                     \
    if (st2) { gld16(pA0h + s2, L256(CUR, 0, 1));                             \
               gld16(pA10 + s2, L256(CUR, 1, 0));                             \
               gld16(pA1h + s2, L256(CUR, 1, 1)); }                           \
    __builtin_amdgcn_s_barrier();                                             \
    __builtin_amdgcn_sched_barrier(0);                                        \
    __builtin_amdgcn_s_setprio(1);                                            \
    _Pragma("unroll") for (int kk = 0; kk < 2; kk++)                          \
      _Pragma("unroll") for (int mi = 0; mi < 4; mi++)                        \
        _Pragma("unroll") for (int ni = 0; ni < 2; ni++)                      \
          acc[4 + mi][ni] = __builtin_amdgcn_mfma_f32_16x16x32_f16(aHi[mi][kk], bA[ni][kk], acc[4 + mi][ni], 0, 0, 0); \
    __builtin_amdgcn_s_setprio(0);                                            \
    if (t < nt - 2)       { asm volatile("s_waitcnt vmcnt(6)" ::: "memory"); }\
    else if (t == nt - 2) { asm volatile("s_waitcnt vmcnt(0)" ::: "memory"); }\
    __builtin_amdgcn_s_barrier();                                             \
  }

#define PRO256()                                                              \
    gld16(pA00, L256(0, 0, 0));                                               \
    gld16(pB00, L256(0, 2, 0)); gld16(pB0h, L256(0, 2, 1));                   \
    gld16(pA0h, L256(0, 0, 1)); gld16(pA10, L256(0, 1, 0)); gld16(pA1h, L256(0, 1, 1)); \
    gld16(pB10, L256(0, 3, 0)); gld16(pB1h, L256(0, 3, 1));                   \
    gld16(pA00 + 128, L256(1, 0, 0));                                         \
    gld16(pB00 + 128, L256(1, 2, 0)); gld16(pB0h + 128, L256(1, 2, 1));       \
    gld16(pA0h + 128, L256(1, 0, 1)); gld16(pA10 + 128, L256(1, 1, 0)); gld16(pA1h + 128, L256(1, 1, 1)); \
    asm volatile("s_waitcnt vmcnt(6)" ::: "memory");                          \
    __builtin_amdgcn_s_barrier();

// ---------------------------------------------------------------------------
// Fused SwiGLU up+gate GEMM (256x128 half-tile pipeline + XCD swizzle).
// One 256x256 GEMM: B panel = [128 rows of w1 | 128 rows of w3]; wc<2 -> U,
// wc>=2 -> G.  Epilogue: G-waves publish acc via LDS, U-waves fuse silu(u)*g.
// ---------------------------------------------------------------------------
__global__ __launch_bounds__(512, 2)
void gemm_dual9(const half_t* __restrict__ A,
                const half_t* __restrict__ B1, const half_t* __restrict__ B2,
                half_t* __restrict__ out, int M, int N, int K)
{
    __shared__ half_t smem[65536];   // 128 KiB
    const int tid = threadIdx.x;
    const int wid = tid >> 6, lane = tid & 63;
    const int lm = lane & 15, lg = lane >> 4;
    const int wr = wid >> 2, wc = wid & 3;
    // XCD swizzle (grid 16x32 = 512, 512%8==0 -> simple bijection)
    const int flat = blockIdx.x + (blockIdx.y << 4);
    const int wg = (flat & 7) * 64 + (flat >> 3);
    const int m0 = (wg & 15) * 256, n0 = (wg >> 4) * 128;

    const size_t KB = (size_t)K * 2;
    const int srow = tid >> 3;
    const int schunk = (tid & 7) ^ (srow & 7);
    const char* pA  = (const char*)A  + (size_t)(m0 + srow) * KB + schunk * 16;
    const char* pB0 = (const char*)B1 + (size_t)(n0 + srow) * KB + schunk * 16;
    const char* pB1 = (const char*)B2 + (size_t)(n0 + srow) * KB + schunk * 16;
    const char* pA00 = pA;
    const char* pA0h = pA + 64 * KB;
    const char* pA10 = pA + 128 * KB;
    const char* pA1h = pA + 192 * KB;
    const char* pB00 = pB0;
    const char* pB0h = pB0 + 64 * KB;
    const char* pB10 = pB1;
    const char* pB1h = pB1 + 64 * KB;
    const int nt = 16;

    char* const lbase = (char*)smem + tid * 16;

    const int swz0 = ((lg ^ (lm & 7)) << 4);
    const int swz1 = (((4 + lg) ^ (lm & 7)) << 4);
    const char* aBase = (const char*)smem + wr * 16384 + lm * 128;
    const char* bBase = (const char*)smem + (2 + (wc >> 1)) * 16384 + (wc & 1) * 8192 + lm * 128;

    PRO256()

    fx4 acc[8][4] = {};

#pragma unroll 1
    for (int tt = 0; tt < 16; tt += 2) {
        { const int t = tt;     KT256(0) }
        { const int t = tt + 1; KT256(1) }
    }

    // ---- epilogue: G-waves publish frags via LDS, U-waves fuse silu(u)*g
    float* gb = (float*)smem;
    if (wc >= 2) {
        const int gw = wr * 2 + (wc - 2);
#pragma unroll
        for (int mi = 0; mi < 8; mi++)
#pragma unroll
            for (int ni = 0; ni < 4; ni++)
                *(fx4*)((char*)gb + ((((gw * 8 + mi) * 4 + ni) * 64 + lane) << 4)) = acc[mi][ni];
    }
    __syncthreads();
    if (wc < 2) {
        const int gw = wr * 2 + wc;
#pragma unroll
        for (int mi = 0; mi < 8; mi++)
#pragma unroll
            for (int ni = 0; ni < 4; ni++) {
                fx4 gv = *(const fx4*)((const char*)gb + ((((gw * 8 + mi) * 4 + ni) * 64 + lane) << 4));
#pragma unroll
                for (int r = 0; r < 4; r++) {
                    int m = m0 + wr * 128 + mi * 16 + lg * 4 + r;
                    int n = n0 + wc * 64 + ni * 16 + lm;
                    float u = acc[mi][ni][r], g = gv[r];
                    out[(size_t)m * N + n] = (half_t)(u / (1.f + __expf(-u)) * g);
                }
            }
    }
}

// ---------------------------------------------------------------------------
// Down-proj 256x256 pipelined GEMM, split-K over blockIdx.z (R17 experiment:
// single-variable re-test of the R2 bundle -- this call site has perfect
// grid fill (16,4,4)=256 blocks=1/CU and nt=16, unlike QKV/O-proj).
// Same verified pipeline as gemm_dual9; plain fp16 partial-store epilogue.
// ---------------------------------------------------------------------------
__global__ __launch_bounds__(512, 2)
void gemm256d(const half_t* __restrict__ A, const half_t* __restrict__ B,
              half_t* o0, half_t* o1, half_t* o2, half_t* o3,
              int M, int N, int K)
{
    __shared__ half_t smem[65536];   // 128 KiB
    const int tid = threadIdx.x;
    const int wid = tid >> 6, lane = tid & 63;
    const int lm = lane & 15, lg = lane >> 4;
    const int wr = wid >> 2, wc = wid & 3;
    const int m0 = blockIdx.x * 256, n0 = blockIdx.y * 256;

    half_t* outb = o0;
    if (blockIdx.z == 1) outb = o1;
    else if (blockIdx.z == 2) outb = o2;
    else if (blockIdx.z == 3) outb = o3;
    const int Keff = K / gridDim.z, koff = blockIdx.z * Keff;
    const int nt = Keff >> 6;                    // 16 for K=4096, z=4

    const size_t KB = (size_t)K * 2;
    const int srow = tid >> 3;
    const int schunk = (tid & 7) ^ (srow & 7);
    const char* pA = (const char*)A + (size_t)(m0 + srow) * KB + (size_t)koff * 2 + schunk * 16;
    const char* pB = (const char*)B + (size_t)(n0 + srow) * KB + (size_t)koff * 2 + schunk * 16;
    const char* pA00 = pA;
    const char* pA0h = pA + 64 * KB;
    const char* pA10 = pA + 128 * KB;
    const char* pA1h = pA + 192 * KB;
    const char* pB00 = pB;
    const char* pB0h = pB + 64 * KB;
    const char* pB10 = pB + 128 * KB;
    const char* pB1h = pB + 192 * KB;

    char* const lbase = (char*)smem + tid * 16;
    const int swz0 = ((lg ^ (lm & 7)) << 4);
    const int swz1 = (((4 + lg) ^ (lm & 7)) << 4);
    const char* aBase = (const char*)smem + wr * 16384 + lm * 128;
    const char* bBase = (const char*)smem + (2 + (wc >> 1)) * 16384 + (wc & 1) * 8192 + lm * 128;

    PRO256()

    fx4 acc[8][4] = {};

#pragma unroll 1
    for (int tt = 0; tt < nt; tt += 2) {
        { const int t = tt;     KT256(0) }
        { const int t = tt + 1; KT256(1) }
    }

#pragma unroll
    for (int mi = 0; mi < 8; mi++)
#pragma unroll
        for (int ni = 0; ni < 4; ni++)
#pragma unroll
            for (int r = 0; r < 4; r++) {
                int m = m0 + wr * 128 + mi * 16 + lg * 4 + r;
                int n = n0 + wc * 64 + ni * 16 + lm;
                outb[(size_t)m * N + n] = (half_t)acc[mi][ni][r];
            }
}

// ---------------------------------------------------------------------------
// Fused O-proj combine + residual + RMSNorm (split-K=2 partials):
//   t = x + p0 + p1;  outF = t;  outH = rmsnorm(t)*w  (fp16)
// ---------------------------------------------------------------------------
__global__ __launch_bounds__(256, 4)
void addnorm_k(const float* __restrict__ x,
               const half_t* __restrict__ p0, const half_t* __restrict__ p1,
               const float* __restrict__ w,
               float* __restrict__ outF, half_t* __restrict__ outH)
{
    int row = blockIdx.x * 4 + (threadIdx.x >> 6);
    int lane = threadIdx.x & 63;
    const float4* xr = (const float4*)(x + (size_t)row * 1024);
    const f16x4* p0r = (const f16x4*)(p0 + (size_t)row * 1024);
    const f16x4* p1r = (const f16x4*)(p1 + (size_t)row * 1024);
    float4 v[4];
    float s = 0.f;
#pragma unroll
    for (int i = 0; i < 4; i++) {
        float4 xv = xr[lane + 64 * i];
        f16x4 a0 = p0r[lane + 64 * i];
        f16x4 a1 = p1r[lane + 64 * i];
        v[i].x = xv.x + (float)a0[0] + (float)a1[0];
        v[i].y = xv.y + (float)a0[1] + (float)a1[1];
        v[i].z = xv.z + (float)a0[2] + (float)a1[2];
        v[i].w = xv.w + (float)a0[3] + (float)a1[3];
        s += v[i].x * v[i].x + v[i].y * v[i].y + v[i].z * v[i].z + v[i].w * v[i].w;
    }
#pragma unroll
    for (int o = 32; o > 0; o >>= 1) s += __shfl_xor(s, o);
    float inv = rsqrtf(s * (1.f / 1024.f) + 1e-5f);
    const float4* w4 = (const float4*)w;
    float4* oF = (float4*)(outF + (size_t)row * 1024);
    f16x4* oH = (f16x4*)(outH + (size_t)row * 1024);
#pragma unroll
    for (int i = 0; i < 4; i++) {
        oF[lane + 64 * i] = v[i];
        float4 wv = w4[lane + 64 * i];
        f16x4 ov = { (half_t)(v[i].x * inv * wv.x), (half_t)(v[i].y * inv * wv.y),
                     (half_t)(v[i].z * inv * wv.z), (half_t)(v[i].w * inv * wv.w) };
        oH[lane + 64 * i] = ov;
    }
}

// ---------------------------------------------------------------------------
// Split-K=4 combine: out = out + p0 + p1 + p2 + p3
// ---------------------------------------------------------------------------
__global__ __launch_bounds__(256, 8)
void reduce4_k(const half_t* __restrict__ p0, const half_t* __restrict__ p1,
               const half_t* __restrict__ p2, const half_t* __restrict__ p3,
               float* __restrict__ out, int n4)
{
    int i = blockIdx.x * 256 + threadIdx.x;
    if (i >= n4) return;
    float4 b = ((const float4*)out)[i];
    f16x4 a0 = ((const f16x4*)p0)[i];
    f16x4 a1 = ((const f16x4*)p1)[i];
    f16x4 a2 = ((const f16x4*)p2)[i];
    f16x4 a3 = ((const f16x4*)p3)[i];
    float4 o = { b.x + (float)a0[0] + (float)a1[0] + (float)a2[0] + (float)a3[0],
                 b.y + (float)a0[1] + (float)a1[1] + (float)a2[1] + (float)a3[1],
                 b.z + (float)a0[2] + (float)a1[2] + (float)a2[2] + (float)a3[2],
                 b.w + (float)a0[3] + (float)a1[3] + (float)a2[3] + (float)a3[3] };
    ((float4*)out)[i] = o;
}

// ---------------------------------------------------------------------------
// Fused: cast 7 weight matrices fp32->fp16 (y<7) + RMSNorm of x (y==7)
// ---------------------------------------------------------------------------
struct CastA { const float* s; half_t* d; int n4; };
struct CastArgs { CastA a[7]; };

__global__ __launch_bounds__(256)
void cast_rms_k(CastArgs ca, const float* __restrict__ x,
                const float* __restrict__ w, half_t* __restrict__ out)
{
    if (blockIdx.y < 7) {
        CastA a = ca.a[blockIdx.y];
        int i = blockIdx.x * 256 + threadIdx.x;
        if (i >= a.n4) return;
        float4 v = ((const float4*)a.s)[i];
        ((f16x4*)a.d)[i] = (f16x4){ (half_t)v.x, (half_t)v.y, (half_t)v.z, (half_t)v.w };
        return;
    }
    if (blockIdx.x >= 1024) return;
    int row = blockIdx.x * 4 + (threadIdx.x >> 6);
    int lane = threadIdx.x & 63;
    const float4* xr = (const float4*)(x + (size_t)row * 1024);
    float4 v[4];
    float s = 0.f;
#pragma unroll
    for (int i = 0; i < 4; i++) {
        v[i] = xr[lane + 64 * i];
        s += v[i].x * v[i].x + v[i].y * v[i].y + v[i].z * v[i].z + v[i].w * v[i].w;
    }
#pragma unroll
    for (int o = 32; o > 0; o >>= 1) s += __shfl_xor(s, o);
    float inv = rsqrtf(s * (1.f / 1024.f) + 1e-5f);
    const float4* w4 = (const float4*)w;
    f16x4* o4 = (f16x4*)(out + (size_t)row * 1024);
#pragma unroll
    for (int i = 0; i < 4; i++) {
        float4 wv = w4[lane + 64 * i];
        f16x4 ov = { (half_t)(v[i].x * inv * wv.x), (half_t)(v[i].y * inv * wv.y),
                     (half_t)(v[i].z * inv * wv.z), (half_t)(v[i].w * inv * wv.w) };
        o4[lane + 64 * i] = ov;
    }
}

// ---------------------------------------------------------------------------
// Causal flash attention, balanced + shuffle-free (R5 best-measured config;
// R6 dbuf and R7 paired-tile variants measured neutral / -9.5us).
// Q,K: [b,h,s,64] (RoPE pre-applied, Q pre-scaled).  VT: [b,h,dk,s].
// XCD swizzle: each XCD owns 4 complete heads -> K/V (2 MB) L2-resident.
// ---------------------------------------------------------------------------
__global__ __launch_bounds__(256, 2)
void attn_k(const half_t* __restrict__ Q, const half_t* __restrict__ K,
            const half_t* __restrict__ VT, half_t* __restrict__ O)
{
    __shared__ half_t sK[128 * 64];
    __shared__ half_t sVT[64 * 128];
    __shared__ half_t sP[4][16 * 128];
    const int tid = threadIdx.x, wid = tid >> 6, lane = tid & 63;
    const int lm = lane & 15, lg = lane >> 4;
    const int flat = blockIdx.x + (blockIdx.y << 4);
    const int wg = (flat & 7) * 64 + (flat >> 3);
    const int p = wg & 15, bh = wg >> 4;
    const int b = bh >> 4, hh = bh & 15;
    const size_t base = (size_t)bh * (2048 * 64);

    const int krow = tid >> 3;
    const int kcsw = ((tid & 7) ^ (krow & 7)) << 4;
    const int vrow = tid >> 4;
    const int vcsw = ((tid & 15) ^ (vrow & 15)) << 4;
    const char* gK = (const char*)(K + base);
    const char* gV = (const char*)(VT + base);
    char* lK = (char*)sK + tid * 16;
    char* lV = (char*)sVT + tid * 16;
    half_t* sPw = sP[wid];

    f16x8 vone;
#pragma unroll
    for (int j = 0; j < 8; j++) vone[j] = (half_t)1.f;

    for (int ph = 0; ph < 2; ph++) {
        const int qt = ph ? (31 - p) : p;
        const int q0 = qt * 64 + wid * 16;
        const int nT = (qt + 2) >> 1;

        f16x8 bQ[2];
#pragma unroll
        for (int ki = 0; ki < 2; ki++)
            bQ[ki] = *(const f16x8*)(Q + base + (size_t)(q0 + lm) * 64 + ki * 32 + lg * 8);

        fx4 oacc[4] = {};
        fx4 lacc = {};

        for (int t = 0; t < nT; t++) {
            const int kv0 = t * 128;
#pragma unroll
            for (int i = 0; i < 4; i++)
                gld16(gK + (size_t)(kv0 + i * 32 + krow) * 128 + kcsw, lK + i * 4096);
#pragma unroll
            for (int i = 0; i < 4; i++)
                gld16(gV + (size_t)(i * 16 + vrow) * 4096 + (size_t)kv0 * 2 + vcsw, lV + i * 4096);
            __syncthreads();

            fx4 st[8] = {};
#pragma unroll
            for (int ki = 0; ki < 2; ki++) {
#pragma unroll
                for (int mi = 0; mi < 8; mi++) {
                    f16x8 aK = *(const f16x8*)(sK + ((mi * 16 + lm) << 6) +
                                               (((ki * 4 + lg) ^ (lm & 7)) << 3));
                    st[mi] = __builtin_amdgcn_mfma_f32_16x16x32_f16(aK, bQ[ki], st[mi], 0, 0, 0);
                }
            }

            const bool diag = (t == nT - 1);
            const int qg = q0 + lm;
#pragma unroll
            for (int mi = 0; mi < 8; mi++) {
                f16x4 ev;
#pragma unroll
                for (int r = 0; r < 4; r++) {
                    float e = __expf(st[mi][r]);
                    if (diag && (kv0 + mi * 16 + lg * 4 + r > qg)) e = 0.f;
                    ev[r] = (half_t)e;
                }
                *(f16x4*)(sPw + (lm << 7) +
                          ((((mi * 2 + (lg >> 1)) ^ lm) << 3) | ((lg & 1) << 2))) = ev;
            }

#pragma unroll
            for (int k2 = 0; k2 < 4; k2++) {
                f16x8 aP = *(const f16x8*)(sPw + (lm << 7) + (((k2 * 4 + lg) ^ lm) << 3));
#pragma unroll
                for (int ni = 0; ni < 4; ni++) {
                    f16x8 bV = *(const f16x8*)(sVT + ((ni * 16 + lm) << 7) +
                                               (((k2 * 4 + lg) ^ lm) << 3));
                    oacc[ni] = __builtin_amdgcn_mfma_f32_16x16x32_f16(aP, bV, oacc[ni], 0, 0, 0);
                }
                lacc = __builtin_amdgcn_mfma_f32_16x16x32_f16(aP, vone, lacc, 0, 0, 0);
            }
            __syncthreads();
        }

        float inv[4];
#pragma unroll
        for (int r = 0; r < 4; r++) inv[r] = 1.f / lacc[r];
#pragma unroll
        for (int ni = 0; ni < 4; ni++)
#pragma unroll
            for (int r = 0; r < 4; r++) {
                int s = q0 + lg * 4 + r;
                O[((size_t)b * 2048 + s) * 1024 + hh * 64 + ni * 16 + lm] =
                    (half_t)(oacc[ni][r] * inv[r]);
            }
    }
}

// ---------------------------------------------------------------------------
// Workspace layout (half_t units, Mi = 1048576):
//   0..1 wq16 | 1..2 wk16 | 2..3 wv16 | 3..4 wo16   (dead after their GEMM)
//   4..8 w116 | 8..12 w316 | 12..16 w216
//   16..20 h16 (attn O) | 20..24 q16 | 24..28 k16 | 28..32 vt16
//   a16 = 16..32 (fused silu(u)*g; q/k/vt/h dead by then)
//   h216 = 32..36
//   O-proj partials  P0@20, P1@24          (q16,k16 dead after attn)
//   down partials    D0@0, D1@4, D2@8, D3@36  (wq..wo, w1, w3 dead)
// Max extent 40 Mi halfs = 80 MiB.
// ---------------------------------------------------------------------------
extern "C" void kernel_launch(void* const* d_in, const int* in_sizes, int n_in,
                              void* d_out, int out_size, void* d_ws, size_t ws_size,
                              hipStream_t stream)
{
    const float* x   = (const float*)d_in[0];
    const float* wq  = (const float*)d_in[1];
    const float* wk  = (const float*)d_in[2];
    const float* wv  = (const float*)d_in[3];
    const float* wo  = (const float*)d_in[4];
    const float* ln1 = (const float*)d_in[5];
    const float* ln2 = (const float*)d_in[6];
    const float* w1  = (const float*)d_in[7];
    const float* w2  = (const float*)d_in[8];
    const float* w3  = (const float*)d_in[9];

    half_t* W = (half_t*)d_ws;
    const size_t Mi = 1048576;
    half_t* wq16 = W;
    half_t* wk16 = W + Mi;
    half_t* wv16 = W + 2 * Mi;
    half_t* wo16 = W + 3 * Mi;
    half_t* w116 = W + 4 * Mi;
    half_t* w316 = W + 8 * Mi;
    half_t* w216 = W + 12 * Mi;
    half_t* h16  = W + 16 * Mi;
    half_t* q16  = W + 20 * Mi;
    half_t* k16  = W + 24 * Mi;
    half_t* vt16 = W + 28 * Mi;
    half_t* a16  = W + 16 * Mi;
    half_t* h216 = W + 32 * Mi;
    half_t* P0   = W + 20 * Mi;
    half_t* P1   = W + 24 * Mi;
    half_t* D0   = W;
    half_t* D1   = W + 4 * Mi;
    half_t* D2   = W + 8 * Mi;
    half_t* D3   = W + 36 * Mi;

    CastArgs ca;
    ca.a[0] = { wq, wq16, 262144 };
    ca.a[1] = { wk, wk16, 262144 };
    ca.a[2] = { wv, wv16, 262144 };
    ca.a[3] = { wo, wo16, 262144 };
    ca.a[4] = { w1, w116, 1048576 };
    ca.a[5] = { w2, w216, 1048576 };
    ca.a[6] = { w3, w316, 1048576 };

    // casts (y<7) + rmsnorm(x) (y==7) in one launch
    cast_rms_k<<<dim3(4096, 8), 256, 0, stream>>>(ca, x, ln1, h16);
    // QKV (128^2 tiles, 2 blk/CU) with fused RoPE (z=0,1) / V^T scatter (z=2)
    gemm_bt<1><<<dim3(32, 8, 3), 256, 0, stream>>>(h16, wq16, wk16, wv16,
                                                   q16, k16, vt16, nullptr,
                                                   4096, 1024, 1024);
    attn_k<<<dim3(16, 32), 256, 0, stream>>>(q16, k16, vt16, h16);
    // O-proj partials (split-K=2)
    gemm_bt<4><<<dim3(32, 8, 2), 256, 0, stream>>>(h16, wo16, nullptr, nullptr,
                                                   P0, P1, nullptr, nullptr,
                                                   4096, 1024, 1024);
    // d_out = x + P0 + P1 ; h216 = rmsnorm(d_out)*ln2   (fused)
    addnorm_k<<<dim3(1024), 256, 0, stream>>>(x, P0, P1, ln2,
                                              (float*)d_out, h216);
    // fused SwiGLU up+gate: a16 = silu(h216·w1^T)*(h216·w3^T)
    gemm_dual9<<<dim3(16, 32), 512, 0, stream>>>(h216, w116, w316, a16,
                                                 4096, 4096, 1024);
    // down-proj partials via 256-pipeline (split-K=4: Keff=1024, nt=16,
    // grid 256 blocks = exact CU fill), then d_out += sum(D)
    gemm256d<<<dim3(16, 4, 4), 512, 0, stream>>>(a16, w216,
                                                 D0, D1, D2, D3,
                                                 4096, 1024, 4096);
    reduce4_k<<<dim3(4096), 256, 0, stream>>>(D0, D1, D2, D3, (float*)d_out, 1048576);
    (void)in_sizes; (void)n_in; (void)out_size; (void)ws_size;
}